// Round 1
// baseline (1488.575 us; speedup 1.0000x reference)
//
#include <hip/hip_runtime.h>
#include <math.h>

#define NN 20000
#define DD 256
#define EE 320000
#define MM 2048
#define CC 10
#define TT 3

// ---------------- device global scratch (avoids ws_size dependency) ----------------
__device__ float g_xbuf[NN * DD];
__device__ float g_h[NN * DD];
__device__ float g_e1[NN * DD];
__device__ float g_e2[NN * DD];
__device__ int   g_cnt[NN];
__device__ int   g_cursor[NN];
__device__ int   g_rowstart[NN + 1];
__device__ float g_dinv[NN];     // deg^-1/2
__device__ float g_invdeg[NN];   // 1/deg
__device__ int   g_srcp[EE];     // src permuted into dst-CSR order
__device__ float g_coefp[EE];    // dinv[src]*dinv[dst] permuted
__device__ float g_sums[CC * DD];
__device__ float g_cntf[CC];
__device__ float g_an[CC * DD];  // normalized class prototypes

__device__ __forceinline__ float wave_sum(float v) {
#pragma unroll
  for (int off = 32; off > 0; off >>= 1) v += __shfl_xor(v, off);
  return v;
}

__device__ __forceinline__ float eluf(float x) {
  return x > 0.f ? x : expm1f(x);
}

// ---------------- graph preprocessing ----------------
__global__ void zero_pre() {
  int i = blockIdx.x * blockDim.x + threadIdx.x;
  if (i < NN) { g_cnt[i] = 0; g_cursor[i] = 0; }
  if (i < CC * DD) g_sums[i] = 0.f;
  if (i < CC) g_cntf[i] = 0.f;
}

__global__ void hist_k(const int* __restrict__ dst) {
  int e = blockIdx.x * blockDim.x + threadIdx.x;
  if (e < EE) atomicAdd(&g_cnt[dst[e]], 1);
}

__global__ void scan_k() {  // single block, 1024 threads, 20 elems/thread
  __shared__ int part[1024];
  int t = threadIdx.x;
  int base = t * 20;
  int s = 0;
#pragma unroll
  for (int j = 0; j < 20; ++j) { int i = base + j; if (i < NN) s += g_cnt[i]; }
  part[t] = s;
  __syncthreads();
  for (int off = 1; off < 1024; off <<= 1) {
    int v = (t >= off) ? part[t - off] : 0;
    __syncthreads();
    part[t] += v;
    __syncthreads();
  }
  int run = (t > 0) ? part[t - 1] : 0;
#pragma unroll
  for (int j = 0; j < 20; ++j) {
    int i = base + j;
    if (i < NN) {
      g_rowstart[i] = run;
      int c = g_cnt[i];
      run += c;
      float dg = (float)(c + 1);
      g_invdeg[i] = 1.0f / dg;
      g_dinv[i] = 1.0f / sqrtf(dg);
    }
  }
  if (t == 1023) g_rowstart[NN] = run;
}

__global__ void fill_k(const int* __restrict__ src, const int* __restrict__ dst) {
  int e = blockIdx.x * blockDim.x + threadIdx.x;
  if (e < EE) {
    int d = dst[e];
    int p = atomicAdd(&g_cursor[d], 1);
    int j = g_rowstart[d] + p;
    int si = src[e];
    g_srcp[j] = si;
    g_coefp[j] = g_dinv[si] * g_dinv[d];
  }
}

// ---------------- GEMM: C[20000,256] = epi(A[20000,256] @ B[256,256]) ----------------
// EPI 0: C = acc
// EPI 1: C = elu(alpha*acc + bias)     (alpha from device scalar, may be null -> 1)
// EPI 2: C = (acc + bias) * mul        (elementwise multiply by matrix `mul`)
template <int EPI>
__global__ __launch_bounds__(256) void gemm_k(const float* __restrict__ A,
                                              const float* __restrict__ B,
                                              float* __restrict__ C,
                                              const float* __restrict__ bias,
                                              const float* __restrict__ alphap,
                                              const float* __restrict__ mul) {
  constexpr int BM = 160, BN = 64, BK = 16;
  __shared__ float As[BK][BM + 4];
  __shared__ float Bs[BK][BN + 4];
  int tid = threadIdx.x;
  int tx = tid & 15, ty = tid >> 4;
  int row0 = blockIdx.x * BM;  // 125 blocks exactly cover 20000
  int col0 = blockIdx.y * BN;  // 4

  float acc[10][4];
#pragma unroll
  for (int i = 0; i < 10; ++i)
#pragma unroll
    for (int j = 0; j < 4; ++j) acc[i][j] = 0.f;

  for (int kt = 0; kt < DD; kt += BK) {
    const float* Ab = A + (size_t)row0 * DD + kt;
    // A tile: 160 rows x 16 k  (640 float4 chunks, float4 along k)
#pragma unroll
    for (int c0 = 0; c0 < 3; ++c0) {
      int c = tid + c0 * 256;
      if (c < 640) {
        int r = c >> 2, kc = (c & 3) << 2;
        float4 v = *(const float4*)(Ab + r * DD + kc);
        As[kc + 0][r] = v.x;
        As[kc + 1][r] = v.y;
        As[kc + 2][r] = v.z;
        As[kc + 3][r] = v.w;
      }
    }
    // B tile: 16 k x 64 cols (256 float4)
    {
      int kb = tid >> 4, cb = (tid & 15) << 2;
      *(float4*)&Bs[kb][cb] = *(const float4*)(B + (size_t)(kt + kb) * DD + col0 + cb);
    }
    __syncthreads();
#pragma unroll
    for (int k = 0; k < BK; ++k) {
      float a[10], b[4];
#pragma unroll
      for (int i = 0; i < 8; ++i) a[i] = As[k][ty * 8 + i];
      a[8] = As[k][128 + ty * 2 + 0];
      a[9] = As[k][128 + ty * 2 + 1];
#pragma unroll
      for (int j = 0; j < 4; ++j) b[j] = Bs[k][tx * 4 + j];
#pragma unroll
      for (int i = 0; i < 10; ++i)
#pragma unroll
        for (int j = 0; j < 4; ++j) acc[i][j] = fmaf(a[i], b[j], acc[i][j]);
    }
    __syncthreads();
  }

  float alpha = 1.f;
  if (EPI == 1 && alphap) alpha = *alphap;
#pragma unroll
  for (int i = 0; i < 10; ++i) {
    int r = (i < 8) ? (ty * 8 + i) : (128 + ty * 2 + (i - 8));
    size_t off = (size_t)(row0 + r) * DD + col0 + tx * 4;
    float vv[4];
#pragma unroll
    for (int j = 0; j < 4; ++j) {
      float xv = acc[i][j];
      if (EPI == 1) {
        xv = fmaf(alpha, xv, bias[col0 + tx * 4 + j]);
        xv = eluf(xv);
      } else if (EPI == 2) {
        xv = (xv + bias[col0 + tx * 4 + j]) * mul[off + j];
      }
      vv[j] = xv;
    }
    float4 v = make_float4(vv[0], vv[1], vv[2], vv[3]);
    *(float4*)(C + off) = v;
  }
}

// ---------------- CSR aggregation with fused conv epilogue ----------------
// out[i,:] = maybe_elu( sum_j coef*h[src] + h[i]*invdeg[i] + bias (+ res[i,:]) )
template <int ELU, int RES>
__global__ __launch_bounds__(256) void agg_k(const float* __restrict__ h,
                                             const float* __restrict__ bias,
                                             const float* __restrict__ res,
                                             float* __restrict__ out) {
  int wid = (blockIdx.x * 256 + threadIdx.x) >> 6;
  int lane = threadIdx.x & 63;
  if (wid >= NN) return;
  const float4* h4 = (const float4*)h;
  float4 acc = make_float4(0.f, 0.f, 0.f, 0.f);
  int s = g_rowstart[wid], e = g_rowstart[wid + 1];
  for (int j = s; j < e; ++j) {
    int sn = g_srcp[j];
    float c = g_coefp[j];
    float4 hv = h4[(size_t)sn * 64 + lane];
    acc.x = fmaf(c, hv.x, acc.x);
    acc.y = fmaf(c, hv.y, acc.y);
    acc.z = fmaf(c, hv.z, acc.z);
    acc.w = fmaf(c, hv.w, acc.w);
  }
  float idg = g_invdeg[wid];
  float4 hv = h4[(size_t)wid * 64 + lane];
  float4 b = ((const float4*)bias)[lane];
  float4 o;
  o.x = acc.x + hv.x * idg + b.x;
  o.y = acc.y + hv.y * idg + b.y;
  o.z = acc.z + hv.z * idg + b.z;
  o.w = acc.w + hv.w * idg + b.w;
  if (RES) {
    float4 rv = ((const float4*)res)[(size_t)wid * 64 + lane];
    o.x += rv.x; o.y += rv.y; o.z += rv.z; o.w += rv.w;
  }
  if (ELU) {
    o.x = eluf(o.x); o.y = eluf(o.y); o.z = eluf(o.z); o.w = eluf(o.w);
  }
  ((float4*)out)[(size_t)wid * 64 + lane] = o;
}

// ---------------- prompt attention: embed = h + softmax(h@aW+ab) @ p_list ----------------
__global__ __launch_bounds__(256) void attn_k(const float* __restrict__ h,
                                              const float* __restrict__ aW,
                                              const float* __restrict__ ab,
                                              const float* __restrict__ plist,
                                              float* __restrict__ out) {
  int wid = (blockIdx.x * 256 + threadIdx.x) >> 6;
  int lane = threadIdx.x & 63;
  if (wid >= NN) return;
  const float4* h4 = (const float4*)h;
  float4 hv = h4[(size_t)wid * 64 + lane];
  int d = lane * 4;
  float lg[5];
#pragma unroll
  for (int k = 0; k < 5; ++k) {
    float p = hv.x * aW[(d + 0) * 5 + k] + hv.y * aW[(d + 1) * 5 + k] +
              hv.z * aW[(d + 2) * 5 + k] + hv.w * aW[(d + 3) * 5 + k];
    lg[k] = wave_sum(p) + ab[k];
  }
  float mx = lg[0];
#pragma unroll
  for (int k = 1; k < 5; ++k) mx = fmaxf(mx, lg[k]);
  float w[5], sum = 0.f;
#pragma unroll
  for (int k = 0; k < 5; ++k) { w[k] = expf(lg[k] - mx); sum += w[k]; }
  float inv = 1.f / sum;
  float4 o = hv;
#pragma unroll
  for (int k = 0; k < 5; ++k) {
    float wk = w[k] * inv;
    float4 pv = ((const float4*)plist)[k * 64 + lane];
    o.x = fmaf(wk, pv.x, o.x);
    o.y = fmaf(wk, pv.y, o.y);
    o.z = fmaf(wk, pv.z, o.z);
    o.w = fmaf(wk, pv.w, o.w);
  }
  ((float4*)out)[(size_t)wid * 64 + lane] = o;
}

// ---------------- class prototypes ----------------
__global__ void proto_k(const float* __restrict__ embed, const int* __restrict__ idx,
                        const int* __restrict__ labels) {
  int m = blockIdx.x;
  int t = threadIdx.x;
  int row = idx[m];
  int lab = labels[m];
  atomicAdd(&g_sums[lab * DD + t], embed[(size_t)row * DD + t]);
  if (t == 0) atomicAdd(&g_cntf[lab], 1.0f);
}

__global__ void protonorm_k() {  // 1 block, 256 threads
  __shared__ float red[4];
  int t = threadIdx.x;
  int lane = t & 63, w = t >> 6;
  for (int c = 0; c < CC; ++c) {
    float v = g_sums[c * DD + t] / fmaxf(g_cntf[c], 1.0f);
    float sq = wave_sum(v * v);
    if (lane == 0) red[w] = sq;
    __syncthreads();
    float tot = red[0] + red[1] + red[2] + red[3];
    float nrm = fmaxf(sqrtf(tot), 1e-8f);
    g_an[c * DD + t] = v / nrm;
    __syncthreads();
  }
}

// ---------------- cosine similarity + softmax ----------------
__global__ __launch_bounds__(256) void cos_k(const float* __restrict__ embed,
                                             const int* __restrict__ idx,
                                             float* __restrict__ out) {
  int wid = (blockIdx.x * 256 + threadIdx.x) >> 6;
  int lane = threadIdx.x & 63;
  if (wid >= MM) return;
  int row = idx[wid];
  const float4* e4 = (const float4*)embed;
  float4 r = e4[(size_t)row * 64 + lane];
  float n = wave_sum(r.x * r.x + r.y * r.y + r.z * r.z + r.w * r.w);
  float rnf = 1.0f / fmaxf(sqrtf(n), 1e-8f);
  float lg[CC];
#pragma unroll
  for (int c = 0; c < CC; ++c) {
    float4 a = ((const float4*)g_an)[c * 64 + lane];
    float p = r.x * a.x + r.y * a.y + r.z * a.z + r.w * a.w;
    lg[c] = wave_sum(p) * rnf;
  }
  float mx = lg[0];
#pragma unroll
  for (int c = 1; c < CC; ++c) mx = fmaxf(mx, lg[c]);
  float s = 0.f, w[CC];
#pragma unroll
  for (int c = 0; c < CC; ++c) { w[c] = expf(lg[c] - mx); s += w[c]; }
  float inv = 1.f / s;
#pragma unroll
  for (int c = 0; c < CC; ++c)
    if (lane == c) out[(size_t)wid * CC + c] = w[c] * inv;
}

// ---------------- host orchestration ----------------
extern "C" void kernel_launch(void* const* d_in, const int* in_sizes, int n_in,
                              void* d_out, int out_size, void* d_ws, size_t ws_size,
                              hipStream_t stream) {
  (void)in_sizes; (void)n_in; (void)d_ws; (void)ws_size; (void)out_size;
  const float* x      = (const float*)d_in[0];
  const int*   src    = (const int*)d_in[1];
  const int*   dst    = (const int*)d_in[2];
  const int*   idx    = (const int*)d_in[3];
  const int*   labels = (const int*)d_in[4];
  const float* W1 = (const float*)d_in[6];
  const float* b1 = (const float*)d_in[7];
  const float* W2 = (const float*)d_in[8];
  const float* b2 = (const float*)d_in[9];
  const float* W3 = (const float*)d_in[10];
  const float* b3 = (const float*)d_in[11];
  const float* cw_in  = (const float*)d_in[12];
  const float* cb_in  = (const float*)d_in[13];
  const float* cw_hid = (const float*)d_in[14];
  const float* cb_hid = (const float*)d_in[15];
  const float* cw_out = (const float*)d_in[16];
  const float* cb_out = (const float*)d_in[17];
  const float* plist  = (const float*)d_in[18];
  const float* aW     = (const float*)d_in[19];
  const float* ab     = (const float*)d_in[20];
  const float* w2s    = (const float*)d_in[21];
  float* out = (float*)d_out;

  float *xbuf, *h, *e1, *e2;
  hipGetSymbolAddress((void**)&xbuf, HIP_SYMBOL(g_xbuf));
  hipGetSymbolAddress((void**)&h,    HIP_SYMBOL(g_h));
  hipGetSymbolAddress((void**)&e1,   HIP_SYMBOL(g_e1));
  hipGetSymbolAddress((void**)&e2,   HIP_SYMBOL(g_e2));

  dim3 gg(125, 4);

  // graph preprocessing (CSR by dst) + zero accumulators
  zero_pre<<<79, 256, 0, stream>>>();
  hist_k<<<1250, 256, 0, stream>>>(dst);
  scan_k<<<1, 1024, 0, stream>>>();
  fill_k<<<1250, 256, 0, stream>>>(src, dst);

  // think layers (e3 is dead code: gcn_weight1 = gcn_weight3 = 0)
  const float* xin = x;
  for (int t = 0; t < TT; ++t) {
    gemm_k<0><<<gg, 256, 0, stream>>>(xin, W1, h, nullptr, nullptr, nullptr);
    agg_k<0, 0><<<5000, 256, 0, stream>>>(h, b1, nullptr, e1);
    gemm_k<0><<<gg, 256, 0, stream>>>(e1, W2, h, nullptr, nullptr, nullptr);
    agg_k<0, 1><<<5000, 256, 0, stream>>>(h, b2, e1, e2);
    // ConditionNet: h1 = elu(w2*e2 @ w_in + b_in); h2 = elu(h1 @ w_hid + b_hid);
    // x = (h2 @ w_out + b_out) * origin_x
    gemm_k<1><<<gg, 256, 0, stream>>>(e2, cw_in + (size_t)t * DD * DD, e1,
                                      cb_in + (size_t)t * DD, w2s, nullptr);
    gemm_k<1><<<gg, 256, 0, stream>>>(e1, cw_hid + (size_t)t * DD * DD, h,
                                      cb_hid + (size_t)t * DD, nullptr, nullptr);
    gemm_k<2><<<gg, 256, 0, stream>>>(h, cw_out + (size_t)t * DD * DD, xbuf,
                                      cb_out + (size_t)t * DD, nullptr, x);
    xin = xbuf;
  }

  // final GCN with ELU
  gemm_k<0><<<gg, 256, 0, stream>>>(xin, W1, h, nullptr, nullptr, nullptr);
  agg_k<1, 0><<<5000, 256, 0, stream>>>(h, b1, nullptr, e1);
  gemm_k<0><<<gg, 256, 0, stream>>>(e1, W2, h, nullptr, nullptr, nullptr);
  agg_k<1, 0><<<5000, 256, 0, stream>>>(h, b2, nullptr, e2);
  gemm_k<0><<<gg, 256, 0, stream>>>(e2, W3, h, nullptr, nullptr, nullptr);
  agg_k<1, 0><<<5000, 256, 0, stream>>>(h, b3, nullptr, e1);

  // prompt attention -> embed (e2)
  attn_k<<<5000, 256, 0, stream>>>(e1, aW, ab, plist, e2);

  // prototypes + cosine softmax
  proto_k<<<MM, 256, 0, stream>>>(e2, idx, labels);
  protonorm_k<<<1, 256, 0, stream>>>();
  cos_k<<<512, 256, 0, stream>>>(e2, idx, out);
}

// Round 2
// 1211.313 us; speedup vs baseline: 1.2289x; 1.2289x over previous
//
#include <hip/hip_runtime.h>
#include <hip/hip_bf16.h>
#include <math.h>

#define NN 20000
#define DD 256
#define EE 320000
#define MM 2048
#define CC 10
#define TT 3

typedef __attribute__((ext_vector_type(8))) short s8v;
typedef __attribute__((ext_vector_type(4))) float f4v;

// ---------------- device global scratch ----------------
__device__ float g_xbuf[NN * DD];
__device__ float g_h[NN * DD];
__device__ float g_e1[NN * DD];
__device__ float g_e2[NN * DD];
__device__ int   g_cnt[NN];
__device__ int   g_cursor[NN];
__device__ int   g_rowstart[NN + 1];
__device__ float g_dinv[NN];
__device__ float g_invdeg[NN];
__device__ int   g_srcp[EE];
__device__ float g_coefp[EE];
__device__ float g_sums[CC * DD];
__device__ float g_cntf[CC];
__device__ float g_an[CC * DD];
// transposed + split weights: wT[n][k], 12 matrices of 256x256 bf16 (hi, lo)
__device__ unsigned short g_wT1[12 * DD * DD];
__device__ unsigned short g_wT2[12 * DD * DD];

__device__ __forceinline__ float wave_sum(float v) {
#pragma unroll
  for (int off = 32; off > 0; off >>= 1) v += __shfl_xor(v, off);
  return v;
}

__device__ __forceinline__ float eluf(float x) {
  return x > 0.f ? x : expm1f(x);
}

// split 8 fp32 -> bf16 hi + bf16 lo fragments (in-register, cvt_pk friendly)
__device__ __forceinline__ void split8(float4 fa, float4 fb, s8v& a1, s8v& a2) {
  float f[8] = {fa.x, fa.y, fa.z, fa.w, fb.x, fb.y, fb.z, fb.w};
  union { s8v v; unsigned short u[8]; } h, l;
#pragma unroll
  for (int i = 0; i < 8; i += 2) {
    float2 p = make_float2(f[i], f[i + 1]);
    __hip_bfloat162 hb = __float22bfloat162_rn(p);
    float2 hf = __bfloat1622float2(hb);
    __hip_bfloat162 lb = __float22bfloat162_rn(make_float2(p.x - hf.x, p.y - hf.y));
    union { __hip_bfloat162 b; unsigned short s[2]; } ch, cl;
    ch.b = hb; cl.b = lb;
    h.u[i] = ch.s[0]; h.u[i + 1] = ch.s[1];
    l.u[i] = cl.s[0]; l.u[i + 1] = cl.s[1];
  }
  a1 = h.v; a2 = l.v;
}

// ---------------- graph preprocessing ----------------
__global__ void zero_pre() {
  int i = blockIdx.x * blockDim.x + threadIdx.x;
  if (i < NN) { g_cnt[i] = 0; g_cursor[i] = 0; }
  if (i < CC * DD) g_sums[i] = 0.f;
  if (i < CC) g_cntf[i] = 0.f;
}

__global__ void hist_k(const int* __restrict__ dst) {
  int e = blockIdx.x * blockDim.x + threadIdx.x;
  if (e < EE) atomicAdd(&g_cnt[dst[e]], 1);
}

__global__ void scan_k() {
  __shared__ int part[1024];
  int t = threadIdx.x;
  int base = t * 20;
  int s = 0;
#pragma unroll
  for (int j = 0; j < 20; ++j) { int i = base + j; if (i < NN) s += g_cnt[i]; }
  part[t] = s;
  __syncthreads();
  for (int off = 1; off < 1024; off <<= 1) {
    int v = (t >= off) ? part[t - off] : 0;
    __syncthreads();
    part[t] += v;
    __syncthreads();
  }
  int run = (t > 0) ? part[t - 1] : 0;
#pragma unroll
  for (int j = 0; j < 20; ++j) {
    int i = base + j;
    if (i < NN) {
      g_rowstart[i] = run;
      int c = g_cnt[i];
      run += c;
      float dg = (float)(c + 1);
      g_invdeg[i] = 1.0f / dg;
      g_dinv[i] = 1.0f / sqrtf(dg);
    }
  }
  if (t == 1023) g_rowstart[NN] = run;
}

__global__ void fill_k(const int* __restrict__ src, const int* __restrict__ dst) {
  int e = blockIdx.x * blockDim.x + threadIdx.x;
  if (e < EE) {
    int d = dst[e];
    int p = atomicAdd(&g_cursor[d], 1);
    int j = g_rowstart[d] + p;
    int si = src[e];
    g_srcp[j] = si;
    g_coefp[j] = g_dinv[si] * g_dinv[d];
  }
}

// ---------------- weight transpose + bf16 split (once per launch) ----------------
struct WPtrs { const float* p[12]; };

__global__ __launch_bounds__(256) void wprep_k(WPtrs wp) {
  __shared__ float t[64][65];
  int widx = blockIdx.z;
  int kt0 = blockIdx.x * 64, nt0 = blockIdx.y * 64;
  const float* W = wp.p[widx];
  int tid = threadIdx.x;
  int ln = tid & 63, lk = tid >> 6;
  for (int kk = lk; kk < 64; kk += 4)
    t[kk][ln] = W[(size_t)(kt0 + kk) * DD + nt0 + ln];
  __syncthreads();
  for (int nn = lk; nn < 64; nn += 4) {
    float v = t[ln][nn];
    __hip_bfloat16 hb = __float2bfloat16(v);
    float hf = __bfloat162float(hb);
    __hip_bfloat16 lb = __float2bfloat16(v - hf);
    union { __hip_bfloat16 b; unsigned short s; } ch, cl;
    ch.b = hb; cl.b = lb;
    size_t o = (size_t)widx * DD * DD + (size_t)(nt0 + nn) * DD + kt0 + ln;
    g_wT1[o] = ch.s;
    g_wT2[o] = cl.s;
  }
}

// ---------------- MFMA GEMM: C[20000,256] = epi(A @ W), bf16x3 split ----------------
// EPI 0: C = acc
// EPI 1: C = elu(alpha*acc + bias)
// EPI 2: C = (acc + bias) * mul
template <int EPI>
__global__ __launch_bounds__(256) void gemm_k(const float* __restrict__ A,
                                              const unsigned short* __restrict__ B1,
                                              const unsigned short* __restrict__ B2,
                                              float* __restrict__ C,
                                              const float* __restrict__ bias,
                                              const float* __restrict__ alphap,
                                              const float* __restrict__ mul) {
  // chunked-XCD swizzle: 4 N-blocks of one M-slice land on the same XCD L2
  int b = blockIdx.x;
  int xcd = b & 7, off = b >> 3;
  int logical = (xcd < 4 ? xcd * 63 : 252 + (xcd - 4) * 62) + off;
  int mblk = logical >> 2, nblk = logical & 3;

  int tid = threadIdx.x;
  int wave = tid >> 6, lane = tid & 63;
  int wm = wave >> 1, wn = wave & 1;
  int lr = lane & 15, lk = lane >> 4;
  int arow = mblk * 160 + wm * 80 + lr;   // + mi*16
  int bcol = nblk * 64 + wn * 32 + lr;    // + nj*16

  f4v acc[5][2];
#pragma unroll
  for (int i = 0; i < 5; ++i)
#pragma unroll
    for (int j = 0; j < 2; ++j) acc[i][j] = (f4v){0.f, 0.f, 0.f, 0.f};

  const float* Abase = A + (size_t)arow * DD;
#pragma unroll
  for (int kt = 0; kt < DD; kt += 32) {
    int ko = kt + lk * 8;
    s8v b1f[2], b2f[2];
#pragma unroll
    for (int nj = 0; nj < 2; ++nj) {
      size_t boff = (size_t)(bcol + nj * 16) * DD + ko;
      b1f[nj] = *(const s8v*)(B1 + boff);
      b2f[nj] = *(const s8v*)(B2 + boff);
    }
#pragma unroll
    for (int mi = 0; mi < 5; ++mi) {
      const float* ap = Abase + (size_t)mi * 16 * DD + ko;
      float4 fa = *(const float4*)ap;
      float4 fb = *(const float4*)(ap + 4);
      s8v a1, a2;
      split8(fa, fb, a1, a2);
#pragma unroll
      for (int nj = 0; nj < 2; ++nj) {
        acc[mi][nj] = __builtin_amdgcn_mfma_f32_16x16x32_bf16(a1, b1f[nj], acc[mi][nj], 0, 0, 0);
        acc[mi][nj] = __builtin_amdgcn_mfma_f32_16x16x32_bf16(a1, b2f[nj], acc[mi][nj], 0, 0, 0);
        acc[mi][nj] = __builtin_amdgcn_mfma_f32_16x16x32_bf16(a2, b1f[nj], acc[mi][nj], 0, 0, 0);
      }
    }
  }

  float alpha = 1.f;
  if (EPI == 1 && alphap) alpha = *alphap;
#pragma unroll
  for (int mi = 0; mi < 5; ++mi) {
    int crow = mblk * 160 + wm * 80 + mi * 16 + lk * 4;
#pragma unroll
    for (int nj = 0; nj < 2; ++nj) {
      int col = bcol + nj * 16;
      float bv = (EPI != 0) ? bias[col] : 0.f;
#pragma unroll
      for (int r = 0; r < 4; ++r) {
        float xv = acc[mi][nj][r];
        size_t o = (size_t)(crow + r) * DD + col;
        if (EPI == 1) {
          xv = eluf(fmaf(alpha, xv, bv));
        } else if (EPI == 2) {
          xv = (xv + bv) * mul[o];
        }
        C[o] = xv;
      }
    }
  }
}

// ---------------- CSR aggregation with fused conv epilogue ----------------
template <int ELU, int RES>
__global__ __launch_bounds__(256) void agg_k(const float* __restrict__ h,
                                             const float* __restrict__ bias,
                                             const float* __restrict__ res,
                                             float* __restrict__ out) {
  int wid = (blockIdx.x * 256 + threadIdx.x) >> 6;
  int lane = threadIdx.x & 63;
  if (wid >= NN) return;
  const float4* h4 = (const float4*)h;
  float4 acc = make_float4(0.f, 0.f, 0.f, 0.f);
  int s = g_rowstart[wid], e = g_rowstart[wid + 1];
  for (int j = s; j < e; ++j) {
    int sn = g_srcp[j];
    float c = g_coefp[j];
    float4 hv = h4[(size_t)sn * 64 + lane];
    acc.x = fmaf(c, hv.x, acc.x);
    acc.y = fmaf(c, hv.y, acc.y);
    acc.z = fmaf(c, hv.z, acc.z);
    acc.w = fmaf(c, hv.w, acc.w);
  }
  float idg = g_invdeg[wid];
  float4 hv = h4[(size_t)wid * 64 + lane];
  float4 b = ((const float4*)bias)[lane];
  float4 o;
  o.x = acc.x + hv.x * idg + b.x;
  o.y = acc.y + hv.y * idg + b.y;
  o.z = acc.z + hv.z * idg + b.z;
  o.w = acc.w + hv.w * idg + b.w;
  if (RES) {
    float4 rv = ((const float4*)res)[(size_t)wid * 64 + lane];
    o.x += rv.x; o.y += rv.y; o.z += rv.z; o.w += rv.w;
  }
  if (ELU) {
    o.x = eluf(o.x); o.y = eluf(o.y); o.z = eluf(o.z); o.w = eluf(o.w);
  }
  ((float4*)out)[(size_t)wid * 64 + lane] = o;
}

// ---------------- prompt attention ----------------
__global__ __launch_bounds__(256) void attn_k(const float* __restrict__ h,
                                              const float* __restrict__ aW,
                                              const float* __restrict__ ab,
                                              const float* __restrict__ plist,
                                              float* __restrict__ out) {
  int wid = (blockIdx.x * 256 + threadIdx.x) >> 6;
  int lane = threadIdx.x & 63;
  if (wid >= NN) return;
  const float4* h4 = (const float4*)h;
  float4 hv = h4[(size_t)wid * 64 + lane];
  int d = lane * 4;
  float lg[5];
#pragma unroll
  for (int k = 0; k < 5; ++k) {
    float p = hv.x * aW[(d + 0) * 5 + k] + hv.y * aW[(d + 1) * 5 + k] +
              hv.z * aW[(d + 2) * 5 + k] + hv.w * aW[(d + 3) * 5 + k];
    lg[k] = wave_sum(p) + ab[k];
  }
  float mx = lg[0];
#pragma unroll
  for (int k = 1; k < 5; ++k) mx = fmaxf(mx, lg[k]);
  float w[5], sum = 0.f;
#pragma unroll
  for (int k = 0; k < 5; ++k) { w[k] = expf(lg[k] - mx); sum += w[k]; }
  float inv = 1.f / sum;
  float4 o = hv;
#pragma unroll
  for (int k = 0; k < 5; ++k) {
    float wk = w[k] * inv;
    float4 pv = ((const float4*)plist)[k * 64 + lane];
    o.x = fmaf(wk, pv.x, o.x);
    o.y = fmaf(wk, pv.y, o.y);
    o.z = fmaf(wk, pv.z, o.z);
    o.w = fmaf(wk, pv.w, o.w);
  }
  ((float4*)out)[(size_t)wid * 64 + lane] = o;
}

// ---------------- class prototypes ----------------
__global__ void proto_k(const float* __restrict__ embed, const int* __restrict__ idx,
                        const int* __restrict__ labels) {
  int m = blockIdx.x;
  int t = threadIdx.x;
  int row = idx[m];
  int lab = labels[m];
  atomicAdd(&g_sums[lab * DD + t], embed[(size_t)row * DD + t]);
  if (t == 0) atomicAdd(&g_cntf[lab], 1.0f);
}

__global__ void protonorm_k() {
  __shared__ float red[4];
  int t = threadIdx.x;
  int lane = t & 63, w = t >> 6;
  for (int c = 0; c < CC; ++c) {
    float v = g_sums[c * DD + t] / fmaxf(g_cntf[c], 1.0f);
    float sq = wave_sum(v * v);
    if (lane == 0) red[w] = sq;
    __syncthreads();
    float tot = red[0] + red[1] + red[2] + red[3];
    float nrm = fmaxf(sqrtf(tot), 1e-8f);
    g_an[c * DD + t] = v / nrm;
    __syncthreads();
  }
}

// ---------------- cosine similarity + softmax ----------------
__global__ __launch_bounds__(256) void cos_k(const float* __restrict__ embed,
                                             const int* __restrict__ idx,
                                             float* __restrict__ out) {
  int wid = (blockIdx.x * 256 + threadIdx.x) >> 6;
  int lane = threadIdx.x & 63;
  if (wid >= MM) return;
  int row = idx[wid];
  const float4* e4 = (const float4*)embed;
  float4 r = e4[(size_t)row * 64 + lane];
  float n = wave_sum(r.x * r.x + r.y * r.y + r.z * r.z + r.w * r.w);
  float rnf = 1.0f / fmaxf(sqrtf(n), 1e-8f);
  float lg[CC];
#pragma unroll
  for (int c = 0; c < CC; ++c) {
    float4 a = ((const float4*)g_an)[c * 64 + lane];
    float p = r.x * a.x + r.y * a.y + r.z * a.z + r.w * a.w;
    lg[c] = wave_sum(p) * rnf;
  }
  float mx = lg[0];
#pragma unroll
  for (int c = 1; c < CC; ++c) mx = fmaxf(mx, lg[c]);
  float s = 0.f, w[CC];
#pragma unroll
  for (int c = 0; c < CC; ++c) { w[c] = expf(lg[c] - mx); s += w[c]; }
  float inv = 1.f / s;
#pragma unroll
  for (int c = 0; c < CC; ++c)
    if (lane == c) out[(size_t)wid * CC + c] = w[c] * inv;
}

// ---------------- host orchestration ----------------
extern "C" void kernel_launch(void* const* d_in, const int* in_sizes, int n_in,
                              void* d_out, int out_size, void* d_ws, size_t ws_size,
                              hipStream_t stream) {
  (void)in_sizes; (void)n_in; (void)d_ws; (void)ws_size; (void)out_size;
  const float* x      = (const float*)d_in[0];
  const int*   src    = (const int*)d_in[1];
  const int*   dst    = (const int*)d_in[2];
  const int*   idx    = (const int*)d_in[3];
  const int*   labels = (const int*)d_in[4];
  const float* W1 = (const float*)d_in[6];
  const float* b1 = (const float*)d_in[7];
  const float* W2 = (const float*)d_in[8];
  const float* b2 = (const float*)d_in[9];
  const float* W3 = (const float*)d_in[10];
  const float* b3 = (const float*)d_in[11];
  const float* cw_in  = (const float*)d_in[12];
  const float* cb_in  = (const float*)d_in[13];
  const float* cw_hid = (const float*)d_in[14];
  const float* cb_hid = (const float*)d_in[15];
  const float* cw_out = (const float*)d_in[16];
  const float* cb_out = (const float*)d_in[17];
  const float* plist  = (const float*)d_in[18];
  const float* aW     = (const float*)d_in[19];
  const float* ab     = (const float*)d_in[20];
  const float* w2s    = (const float*)d_in[21];
  float* out = (float*)d_out;

  float *xbuf, *h, *e1, *e2;
  unsigned short *wt1, *wt2;
  hipGetSymbolAddress((void**)&xbuf, HIP_SYMBOL(g_xbuf));
  hipGetSymbolAddress((void**)&h,    HIP_SYMBOL(g_h));
  hipGetSymbolAddress((void**)&e1,   HIP_SYMBOL(g_e1));
  hipGetSymbolAddress((void**)&e2,   HIP_SYMBOL(g_e2));
  hipGetSymbolAddress((void**)&wt1,  HIP_SYMBOL(g_wT1));
  hipGetSymbolAddress((void**)&wt2,  HIP_SYMBOL(g_wT2));

  auto WT1 = [&](int w) { return (const unsigned short*)(wt1 + (size_t)w * DD * DD); };
  auto WT2 = [&](int w) { return (const unsigned short*)(wt2 + (size_t)w * DD * DD); };

  // preprocessing: CSR + weight transpose/split
  zero_pre<<<79, 256, 0, stream>>>();
  hist_k<<<1250, 256, 0, stream>>>(dst);
  scan_k<<<1, 1024, 0, stream>>>();
  fill_k<<<1250, 256, 0, stream>>>(src, dst);

  WPtrs wp;
  wp.p[0] = W1; wp.p[1] = W2; wp.p[2] = W3;
  for (int t = 0; t < 3; ++t) {
    wp.p[3 + t] = cw_in  + (size_t)t * DD * DD;
    wp.p[6 + t] = cw_hid + (size_t)t * DD * DD;
    wp.p[9 + t] = cw_out + (size_t)t * DD * DD;
  }
  wprep_k<<<dim3(4, 4, 12), 256, 0, stream>>>(wp);

  // think layers (e3 is dead: gcn_weight1 = gcn_weight3 = 0)
  const float* xin = x;
  for (int t = 0; t < TT; ++t) {
    gemm_k<0><<<500, 256, 0, stream>>>(xin, WT1(0), WT2(0), h, nullptr, nullptr, nullptr);
    agg_k<0, 0><<<5000, 256, 0, stream>>>(h, b1, nullptr, e1);
    gemm_k<0><<<500, 256, 0, stream>>>(e1, WT1(1), WT2(1), h, nullptr, nullptr, nullptr);
    agg_k<0, 1><<<5000, 256, 0, stream>>>(h, b2, e1, e2);
    gemm_k<1><<<500, 256, 0, stream>>>(e2, WT1(3 + t), WT2(3 + t), e1,
                                       cb_in + (size_t)t * DD, w2s, nullptr);
    gemm_k<1><<<500, 256, 0, stream>>>(e1, WT1(6 + t), WT2(6 + t), h,
                                       cb_hid + (size_t)t * DD, nullptr, nullptr);
    gemm_k<2><<<500, 256, 0, stream>>>(h, WT1(9 + t), WT2(9 + t), xbuf,
                                       cb_out + (size_t)t * DD, nullptr, x);
    xin = xbuf;
  }

  // final GCN with ELU
  gemm_k<0><<<500, 256, 0, stream>>>(xin, WT1(0), WT2(0), h, nullptr, nullptr, nullptr);
  agg_k<1, 0><<<5000, 256, 0, stream>>>(h, b1, nullptr, e1);
  gemm_k<0><<<500, 256, 0, stream>>>(e1, WT1(1), WT2(1), h, nullptr, nullptr, nullptr);
  agg_k<1, 0><<<5000, 256, 0, stream>>>(h, b2, nullptr, e2);
  gemm_k<0><<<500, 256, 0, stream>>>(e2, WT1(2), WT2(2), h, nullptr, nullptr, nullptr);
  agg_k<1, 0><<<5000, 256, 0, stream>>>(h, b3, nullptr, e1);

  // prompt attention -> embed (e2)
  attn_k<<<5000, 256, 0, stream>>>(e1, aW, ab, plist, e2);

  // prototypes + cosine softmax
  proto_k<<<MM, 256, 0, stream>>>(e2, idx, labels);
  protonorm_k<<<1, 256, 0, stream>>>();
  cos_k<<<512, 256, 0, stream>>>(e2, idx, out);
}

// Round 3
// 1143.270 us; speedup vs baseline: 1.3020x; 1.0595x over previous
//
#include <hip/hip_runtime.h>
#include <hip/hip_bf16.h>
#include <math.h>

#define NN 20000
#define DD 256
#define EE 320000
#define MM 2048
#define CC 10
#define TT 3

typedef __attribute__((ext_vector_type(8))) short s8v;
typedef __attribute__((ext_vector_type(4))) float f4v;

// ---------------- device global scratch ----------------
__device__ float g_xbuf[NN * DD];
__device__ float g_h[NN * DD];
__device__ float g_e1[NN * DD];
__device__ float g_e2[NN * DD];
__device__ int   g_cnt[NN];
__device__ int   g_cursor[NN];
__device__ int   g_rowstart[NN + 1];
__device__ float g_dinv[NN];
__device__ float g_invdeg[NN];
__device__ int2  g_edge[EE];     // {src, coef bits} in dst-CSR order
__device__ float g_sums[CC * DD];
__device__ float g_cntf[CC];
__device__ float g_an[CC * DD];
// transposed + split weights: wT[n][k], 12 matrices of 256x256 bf16 (hi, lo)
__device__ unsigned short g_wT1[12 * DD * DD];
__device__ unsigned short g_wT2[12 * DD * DD];

__device__ __forceinline__ float wave_sum(float v) {
#pragma unroll
  for (int off = 32; off > 0; off >>= 1) v += __shfl_xor(v, off);
  return v;
}

__device__ __forceinline__ float eluf(float x) {
  return x > 0.f ? x : expm1f(x);
}

// split 8 fp32 -> bf16 hi + bf16 lo fragments
__device__ __forceinline__ void split8(float4 fa, float4 fb, s8v& a1, s8v& a2) {
  float f[8] = {fa.x, fa.y, fa.z, fa.w, fb.x, fb.y, fb.z, fb.w};
  union { s8v v; unsigned short u[8]; } h, l;
#pragma unroll
  for (int i = 0; i < 8; i += 2) {
    float2 p = make_float2(f[i], f[i + 1]);
    __hip_bfloat162 hb = __float22bfloat162_rn(p);
    float2 hf = __bfloat1622float2(hb);
    __hip_bfloat162 lb = __float22bfloat162_rn(make_float2(p.x - hf.x, p.y - hf.y));
    union { __hip_bfloat162 b; unsigned short s[2]; } ch, cl;
    ch.b = hb; cl.b = lb;
    h.u[i] = ch.s[0]; h.u[i + 1] = ch.s[1];
    l.u[i] = cl.s[0]; l.u[i + 1] = cl.s[1];
  }
  a1 = h.v; a2 = l.v;
}

// ---------------- graph preprocessing ----------------
__global__ void zero_pre() {
  int i = blockIdx.x * blockDim.x + threadIdx.x;
  if (i < NN) { g_cnt[i] = 0; g_cursor[i] = 0; }
  if (i < CC * DD) g_sums[i] = 0.f;
  if (i < CC) g_cntf[i] = 0.f;
}

__global__ void hist_k(const int* __restrict__ dst) {
  int e = blockIdx.x * blockDim.x + threadIdx.x;
  if (e < EE) atomicAdd(&g_cnt[dst[e]], 1);
}

__global__ void scan_k() {
  __shared__ int part[1024];
  int t = threadIdx.x;
  int base = t * 20;
  int s = 0;
#pragma unroll
  for (int j = 0; j < 20; ++j) { int i = base + j; if (i < NN) s += g_cnt[i]; }
  part[t] = s;
  __syncthreads();
  for (int off = 1; off < 1024; off <<= 1) {
    int v = (t >= off) ? part[t - off] : 0;
    __syncthreads();
    part[t] += v;
    __syncthreads();
  }
  int run = (t > 0) ? part[t - 1] : 0;
#pragma unroll
  for (int j = 0; j < 20; ++j) {
    int i = base + j;
    if (i < NN) {
      g_rowstart[i] = run;
      int c = g_cnt[i];
      run += c;
      float dg = (float)(c + 1);
      g_invdeg[i] = 1.0f / dg;
      g_dinv[i] = 1.0f / sqrtf(dg);
    }
  }
  if (t == 1023) g_rowstart[NN] = run;
}

__global__ void fill_k(const int* __restrict__ src, const int* __restrict__ dst) {
  int e = blockIdx.x * blockDim.x + threadIdx.x;
  if (e < EE) {
    int d = dst[e];
    int p = atomicAdd(&g_cursor[d], 1);
    int j = g_rowstart[d] + p;
    int si = src[e];
    float coef = g_dinv[si] * g_dinv[d];
    g_edge[j] = make_int2(si, __float_as_int(coef));
  }
}

// ---------------- weight transpose + bf16 split ----------------
struct WPtrs { const float* p[12]; };

__global__ __launch_bounds__(256) void wprep_k(WPtrs wp) {
  __shared__ float t[64][65];
  int widx = blockIdx.z;
  int kt0 = blockIdx.x * 64, nt0 = blockIdx.y * 64;
  const float* W = wp.p[widx];
  int tid = threadIdx.x;
  int ln = tid & 63, lk = tid >> 6;
  for (int kk = lk; kk < 64; kk += 4)
    t[kk][ln] = W[(size_t)(kt0 + kk) * DD + nt0 + ln];
  __syncthreads();
  for (int nn = lk; nn < 64; nn += 4) {
    float v = t[ln][nn];
    __hip_bfloat16 hb = __float2bfloat16(v);
    float hf = __bfloat162float(hb);
    __hip_bfloat16 lb = __float2bfloat16(v - hf);
    union { __hip_bfloat16 b; unsigned short s; } ch, cl;
    ch.b = hb; cl.b = lb;
    size_t o = (size_t)widx * DD * DD + (size_t)(nt0 + nn) * DD + kt0 + ln;
    g_wT1[o] = ch.s;
    g_wT2[o] = cl.s;
  }
}

// ---------------- MFMA GEMM: C[20000,256] = epi(A @ W), bf16x3 split ----------------
template <int EPI>
__global__ __launch_bounds__(256) void gemm_k(const float* __restrict__ A,
                                              const unsigned short* __restrict__ B1,
                                              const unsigned short* __restrict__ B2,
                                              float* __restrict__ C,
                                              const float* __restrict__ bias,
                                              const float* __restrict__ alphap,
                                              const float* __restrict__ mul) {
  int b = blockIdx.x;
  int xcd = b & 7, off = b >> 3;
  int logical = (xcd < 4 ? xcd * 63 : 252 + (xcd - 4) * 62) + off;
  int mblk = logical >> 2, nblk = logical & 3;

  int tid = threadIdx.x;
  int wave = tid >> 6, lane = tid & 63;
  int wm = wave >> 1, wn = wave & 1;
  int lr = lane & 15, lk = lane >> 4;
  int arow = mblk * 160 + wm * 80 + lr;
  int bcol = nblk * 64 + wn * 32 + lr;

  f4v acc[5][2];
#pragma unroll
  for (int i = 0; i < 5; ++i)
#pragma unroll
    for (int j = 0; j < 2; ++j) acc[i][j] = (f4v){0.f, 0.f, 0.f, 0.f};

  const float* Abase = A + (size_t)arow * DD;
#pragma unroll
  for (int kt = 0; kt < DD; kt += 32) {
    int ko = kt + lk * 8;
    s8v b1f[2], b2f[2];
#pragma unroll
    for (int nj = 0; nj < 2; ++nj) {
      size_t boff = (size_t)(bcol + nj * 16) * DD + ko;
      b1f[nj] = *(const s8v*)(B1 + boff);
      b2f[nj] = *(const s8v*)(B2 + boff);
    }
#pragma unroll
    for (int mi = 0; mi < 5; ++mi) {
      const float* ap = Abase + (size_t)mi * 16 * DD + ko;
      float4 fa = *(const float4*)ap;
      float4 fb = *(const float4*)(ap + 4);
      s8v a1, a2;
      split8(fa, fb, a1, a2);
#pragma unroll
      for (int nj = 0; nj < 2; ++nj) {
        acc[mi][nj] = __builtin_amdgcn_mfma_f32_16x16x32_bf16(a1, b1f[nj], acc[mi][nj], 0, 0, 0);
        acc[mi][nj] = __builtin_amdgcn_mfma_f32_16x16x32_bf16(a1, b2f[nj], acc[mi][nj], 0, 0, 0);
        acc[mi][nj] = __builtin_amdgcn_mfma_f32_16x16x32_bf16(a2, b1f[nj], acc[mi][nj], 0, 0, 0);
      }
    }
  }

  float alpha = 1.f;
  if (EPI == 1 && alphap) alpha = *alphap;
#pragma unroll
  for (int mi = 0; mi < 5; ++mi) {
    int crow = mblk * 160 + wm * 80 + mi * 16 + lk * 4;
#pragma unroll
    for (int nj = 0; nj < 2; ++nj) {
      int col = bcol + nj * 16;
      float bv = (EPI != 0) ? bias[col] : 0.f;
#pragma unroll
      for (int r = 0; r < 4; ++r) {
        float xv = acc[mi][nj][r];
        size_t o = (size_t)(crow + r) * DD + col;
        if (EPI == 1) {
          xv = eluf(fmaf(alpha, xv, bv));
        } else if (EPI == 2) {
          xv = (xv + bv) * mul[o];
        }
        C[o] = xv;
      }
    }
  }
}

// ---------------- CSR aggregation core: returns conv output row (one float4/lane) ----
template <int RES>
__device__ __forceinline__ float4 agg_row(int wid, int lane,
                                          const float* __restrict__ h,
                                          const float* __restrict__ bias,
                                          const float* __restrict__ res) {
  const float4* h4 = (const float4*)h;
  float4 a0 = make_float4(0.f, 0.f, 0.f, 0.f);
  float4 a1 = make_float4(0.f, 0.f, 0.f, 0.f);
  int s = g_rowstart[wid], e = g_rowstart[wid + 1];
  int j = s;
  // 8-wide unrolled main loop: 8 gathers in flight per wave
  for (; j + 8 <= e; j += 8) {
    int2 E[8];
    float4 v[8];
#pragma unroll
    for (int u = 0; u < 8; ++u) E[u] = g_edge[j + u];
#pragma unroll
    for (int u = 0; u < 8; ++u) v[u] = h4[(size_t)E[u].x * 64 + lane];
#pragma unroll
    for (int u = 0; u < 8; ++u) {
      float c = __int_as_float(E[u].y);
      float4& a = (u & 1) ? a1 : a0;
      a.x = fmaf(c, v[u].x, a.x);
      a.y = fmaf(c, v[u].y, a.y);
      a.z = fmaf(c, v[u].z, a.z);
      a.w = fmaf(c, v[u].w, a.w);
    }
  }
  // 2-wide tail
  for (; j + 2 <= e; j += 2) {
    int2 E0 = g_edge[j], E1 = g_edge[j + 1];
    float4 v0 = h4[(size_t)E0.x * 64 + lane];
    float4 v1 = h4[(size_t)E1.x * 64 + lane];
    float c0 = __int_as_float(E0.y), c1 = __int_as_float(E1.y);
    a0.x = fmaf(c0, v0.x, a0.x); a0.y = fmaf(c0, v0.y, a0.y);
    a0.z = fmaf(c0, v0.z, a0.z); a0.w = fmaf(c0, v0.w, a0.w);
    a1.x = fmaf(c1, v1.x, a1.x); a1.y = fmaf(c1, v1.y, a1.y);
    a1.z = fmaf(c1, v1.z, a1.z); a1.w = fmaf(c1, v1.w, a1.w);
  }
  if (j < e) {
    int2 E0 = g_edge[j];
    float4 v0 = h4[(size_t)E0.x * 64 + lane];
    float c0 = __int_as_float(E0.y);
    a0.x = fmaf(c0, v0.x, a0.x); a0.y = fmaf(c0, v0.y, a0.y);
    a0.z = fmaf(c0, v0.z, a0.z); a0.w = fmaf(c0, v0.w, a0.w);
  }
  float idg = g_invdeg[wid];
  float4 hv = h4[(size_t)wid * 64 + lane];
  float4 bv = ((const float4*)bias)[lane];
  float4 o;
  o.x = a0.x + a1.x + hv.x * idg + bv.x;
  o.y = a0.y + a1.y + hv.y * idg + bv.y;
  o.z = a0.z + a1.z + hv.z * idg + bv.z;
  o.w = a0.w + a1.w + hv.w * idg + bv.w;
  if (RES) {
    float4 rv = ((const float4*)res)[(size_t)wid * 64 + lane];
    o.x += rv.x; o.y += rv.y; o.z += rv.z; o.w += rv.w;
  }
  return o;
}

template <int ELU, int RES>
__global__ __launch_bounds__(256) void agg_k(const float* __restrict__ h,
                                             const float* __restrict__ bias,
                                             const float* __restrict__ res,
                                             float* __restrict__ out) {
  int wid = (blockIdx.x * 256 + threadIdx.x) >> 6;
  int lane = threadIdx.x & 63;
  if (wid >= NN) return;
  float4 o = agg_row<RES>(wid, lane, h, bias, res);
  if (ELU) {
    o.x = eluf(o.x); o.y = eluf(o.y); o.z = eluf(o.z); o.w = eluf(o.w);
  }
  ((float4*)out)[(size_t)wid * 64 + lane] = o;
}

// final layer: agg + ELU + prompt attention fused (row already in registers)
__global__ __launch_bounds__(256) void aggattn_k(const float* __restrict__ h,
                                                 const float* __restrict__ bias,
                                                 const float* __restrict__ aW,
                                                 const float* __restrict__ ab,
                                                 const float* __restrict__ plist,
                                                 float* __restrict__ out) {
  int wid = (blockIdx.x * 256 + threadIdx.x) >> 6;
  int lane = threadIdx.x & 63;
  if (wid >= NN) return;
  float4 o = agg_row<0>(wid, lane, h, bias, nullptr);
  o.x = eluf(o.x); o.y = eluf(o.y); o.z = eluf(o.z); o.w = eluf(o.w);
  int d = lane * 4;
  float lg[5];
#pragma unroll
  for (int k = 0; k < 5; ++k) {
    float p = o.x * aW[(d + 0) * 5 + k] + o.y * aW[(d + 1) * 5 + k] +
              o.z * aW[(d + 2) * 5 + k] + o.w * aW[(d + 3) * 5 + k];
    lg[k] = wave_sum(p) + ab[k];
  }
  float mx = lg[0];
#pragma unroll
  for (int k = 1; k < 5; ++k) mx = fmaxf(mx, lg[k]);
  float w[5], sum = 0.f;
#pragma unroll
  for (int k = 0; k < 5; ++k) { w[k] = expf(lg[k] - mx); sum += w[k]; }
  float inv = 1.f / sum;
#pragma unroll
  for (int k = 0; k < 5; ++k) {
    float wk = w[k] * inv;
    float4 pv = ((const float4*)plist)[k * 64 + lane];
    o.x = fmaf(wk, pv.x, o.x);
    o.y = fmaf(wk, pv.y, o.y);
    o.z = fmaf(wk, pv.z, o.z);
    o.w = fmaf(wk, pv.w, o.w);
  }
  ((float4*)out)[(size_t)wid * 64 + lane] = o;
}

// ---------------- class prototypes: LDS column-owned partials ----------------
__global__ __launch_bounds__(256) void proto_k(const float* __restrict__ embed,
                                               const int* __restrict__ idxp,
                                               const int* __restrict__ labels) {
  __shared__ float sums[CC][DD];
  __shared__ float cnts[CC];
  int t = threadIdx.x;
#pragma unroll
  for (int c = 0; c < CC; ++c) sums[c][t] = 0.f;
  if (t < CC) cnts[t] = 0.f;
  __syncthreads();
  int m0 = blockIdx.x * 32;  // 64 blocks x 32 rows
  for (int r0 = 0; r0 < 32; r0 += 4) {
    int i4[4], l4[4];
    float v[4];
#pragma unroll
    for (int u = 0; u < 4; ++u) {
      int m = m0 + r0 + u;
      i4[u] = idxp[m];
      l4[u] = labels[m];
    }
#pragma unroll
    for (int u = 0; u < 4; ++u) v[u] = embed[(size_t)i4[u] * DD + t];
#pragma unroll
    for (int u = 0; u < 4; ++u) sums[l4[u]][t] += v[u];
    if (t == 0) {
#pragma unroll
      for (int u = 0; u < 4; ++u) cnts[l4[u]] += 1.f;
    }
  }
  __syncthreads();
#pragma unroll
  for (int c = 0; c < CC; ++c) atomicAdd(&g_sums[c * DD + t], sums[c][t]);
  if (t < CC) atomicAdd(&g_cntf[t], cnts[t]);
}

__global__ void protonorm_k() {
  __shared__ float red[4];
  int t = threadIdx.x;
  int lane = t & 63, w = t >> 6;
  for (int c = 0; c < CC; ++c) {
    float v = g_sums[c * DD + t] / fmaxf(g_cntf[c], 1.0f);
    float sq = wave_sum(v * v);
    if (lane == 0) red[w] = sq;
    __syncthreads();
    float tot = red[0] + red[1] + red[2] + red[3];
    float nrm = fmaxf(sqrtf(tot), 1e-8f);
    g_an[c * DD + t] = v / nrm;
    __syncthreads();
  }
}

// ---------------- cosine similarity + softmax ----------------
__global__ __launch_bounds__(256) void cos_k(const float* __restrict__ embed,
                                             const int* __restrict__ idxp,
                                             float* __restrict__ out) {
  int wid = (blockIdx.x * 256 + threadIdx.x) >> 6;
  int lane = threadIdx.x & 63;
  if (wid >= MM) return;
  int row = idxp[wid];
  const float4* e4 = (const float4*)embed;
  float4 r = e4[(size_t)row * 64 + lane];
  float n = wave_sum(r.x * r.x + r.y * r.y + r.z * r.z + r.w * r.w);
  float rnf = 1.0f / fmaxf(sqrtf(n), 1e-8f);
  float lg[CC];
#pragma unroll
  for (int c = 0; c < CC; ++c) {
    float4 a = ((const float4*)g_an)[c * 64 + lane];
    float p = r.x * a.x + r.y * a.y + r.z * a.z + r.w * a.w;
    lg[c] = wave_sum(p) * rnf;
  }
  float mx = lg[0];
#pragma unroll
  for (int c = 1; c < CC; ++c) mx = fmaxf(mx, lg[c]);
  float s = 0.f, w[CC];
#pragma unroll
  for (int c = 0; c < CC; ++c) { w[c] = expf(lg[c] - mx); s += w[c]; }
  float inv = 1.f / s;
#pragma unroll
  for (int c = 0; c < CC; ++c)
    if (lane == c) out[(size_t)wid * CC + c] = w[c] * inv;
}

// ---------------- host orchestration ----------------
extern "C" void kernel_launch(void* const* d_in, const int* in_sizes, int n_in,
                              void* d_out, int out_size, void* d_ws, size_t ws_size,
                              hipStream_t stream) {
  (void)in_sizes; (void)n_in; (void)d_ws; (void)ws_size; (void)out_size;
  const float* x      = (const float*)d_in[0];
  const int*   src    = (const int*)d_in[1];
  const int*   dst    = (const int*)d_in[2];
  const int*   idx    = (const int*)d_in[3];
  const int*   labels = (const int*)d_in[4];
  const float* W1 = (const float*)d_in[6];
  const float* b1 = (const float*)d_in[7];
  const float* W2 = (const float*)d_in[8];
  const float* b2 = (const float*)d_in[9];
  const float* W3 = (const float*)d_in[10];
  const float* b3 = (const float*)d_in[11];
  const float* cw_in  = (const float*)d_in[12];
  const float* cb_in  = (const float*)d_in[13];
  const float* cw_hid = (const float*)d_in[14];
  const float* cb_hid = (const float*)d_in[15];
  const float* cw_out = (const float*)d_in[16];
  const float* cb_out = (const float*)d_in[17];
  const float* plist  = (const float*)d_in[18];
  const float* aW     = (const float*)d_in[19];
  const float* ab     = (const float*)d_in[20];
  const float* w2s    = (const float*)d_in[21];
  float* out = (float*)d_out;

  float *xbuf, *h, *e1, *e2;
  unsigned short *wt1, *wt2;
  hipGetSymbolAddress((void**)&xbuf, HIP_SYMBOL(g_xbuf));
  hipGetSymbolAddress((void**)&h,    HIP_SYMBOL(g_h));
  hipGetSymbolAddress((void**)&e1,   HIP_SYMBOL(g_e1));
  hipGetSymbolAddress((void**)&e2,   HIP_SYMBOL(g_e2));
  hipGetSymbolAddress((void**)&wt1,  HIP_SYMBOL(g_wT1));
  hipGetSymbolAddress((void**)&wt2,  HIP_SYMBOL(g_wT2));

  auto WT1 = [&](int w) { return (const unsigned short*)(wt1 + (size_t)w * DD * DD); };
  auto WT2 = [&](int w) { return (const unsigned short*)(wt2 + (size_t)w * DD * DD); };

  // preprocessing
  zero_pre<<<79, 256, 0, stream>>>();
  hist_k<<<1250, 256, 0, stream>>>(dst);
  scan_k<<<1, 1024, 0, stream>>>();
  fill_k<<<1250, 256, 0, stream>>>(src, dst);

  WPtrs wp;
  wp.p[0] = W1; wp.p[1] = W2; wp.p[2] = W3;
  for (int t = 0; t < 3; ++t) {
    wp.p[3 + t] = cw_in  + (size_t)t * DD * DD;
    wp.p[6 + t] = cw_hid + (size_t)t * DD * DD;
    wp.p[9 + t] = cw_out + (size_t)t * DD * DD;
  }
  wprep_k<<<dim3(4, 4, 12), 256, 0, stream>>>(wp);

  // think layers (e3 dead: gcn_weight1 = gcn_weight3 = 0)
  const float* xin = x;
  for (int t = 0; t < TT; ++t) {
    gemm_k<0><<<500, 256, 0, stream>>>(xin, WT1(0), WT2(0), h, nullptr, nullptr, nullptr);
    agg_k<0, 0><<<5000, 256, 0, stream>>>(h, b1, nullptr, e1);
    gemm_k<0><<<500, 256, 0, stream>>>(e1, WT1(1), WT2(1), h, nullptr, nullptr, nullptr);
    agg_k<0, 1><<<5000, 256, 0, stream>>>(h, b2, e1, e2);
    gemm_k<1><<<500, 256, 0, stream>>>(e2, WT1(3 + t), WT2(3 + t), e1,
                                       cb_in + (size_t)t * DD, w2s, nullptr);
    gemm_k<1><<<500, 256, 0, stream>>>(e1, WT1(6 + t), WT2(6 + t), h,
                                       cb_hid + (size_t)t * DD, nullptr, nullptr);
    gemm_k<2><<<500, 256, 0, stream>>>(h, WT1(9 + t), WT2(9 + t), xbuf,
                                       cb_out + (size_t)t * DD, nullptr, x);
    xin = xbuf;
  }

  // final GCN with ELU; last layer fuses prompt attention
  gemm_k<0><<<500, 256, 0, stream>>>(xin, WT1(0), WT2(0), h, nullptr, nullptr, nullptr);
  agg_k<1, 0><<<5000, 256, 0, stream>>>(h, b1, nullptr, e1);
  gemm_k<0><<<500, 256, 0, stream>>>(e1, WT1(1), WT2(1), h, nullptr, nullptr, nullptr);
  agg_k<1, 0><<<5000, 256, 0, stream>>>(h, b2, nullptr, e2);
  gemm_k<0><<<500, 256, 0, stream>>>(e2, WT1(2), WT2(2), h, nullptr, nullptr, nullptr);
  aggattn_k<<<5000, 256, 0, stream>>>(h, b3, aW, ab, plist, e2);

  // prototypes + cosine softmax
  proto_k<<<64, 256, 0, stream>>>(e2, idx, labels);
  protonorm_k<<<1, 256, 0, stream>>>();
  cos_k<<<512, 256, 0, stream>>>(e2, idx, out);
}

// Round 4
// 964.044 us; speedup vs baseline: 1.5441x; 1.1859x over previous
//
#include <hip/hip_runtime.h>
#include <hip/hip_bf16.h>
#include <math.h>

#define NN 20000
#define DD 256
#define EE 320000
#define MM 2048
#define CC 10
#define TT 3

typedef __attribute__((ext_vector_type(8))) short s8v;
typedef __attribute__((ext_vector_type(4))) float f4v;

// ---------------- device global scratch ----------------
__device__ unsigned short g_xb[NN * DD];   // bf16 original x
__device__ unsigned short g_xo[NN * DD];   // bf16 evolving x
__device__ unsigned short g_hb[NN * DD];
__device__ unsigned short g_e1b[NN * DD];
__device__ unsigned short g_e2b[NN * DD];
__device__ int   g_cnt[NN];
__device__ int   g_cursor[NN];
__device__ int   g_rowstart[NN + 1];
__device__ float g_dinv[NN];
__device__ float g_invdeg[NN];
__device__ int2  g_edge[EE];     // {src, coef bits} in dst-CSR order
__device__ float g_sums[CC * DD];
__device__ float g_cntf[CC];
__device__ float g_an[CC * DD];
// transposed + split weights: wT[n][k], 12 matrices of 256x256 bf16 (hi, lo)
__device__ unsigned short g_wT1[12 * DD * DD];
__device__ unsigned short g_wT2[12 * DD * DD];

__device__ __forceinline__ float wave_sum(float v) {
#pragma unroll
  for (int off = 32; off > 0; off >>= 1) v += __shfl_xor(v, off);
  return v;
}

__device__ __forceinline__ float eluf(float x) {
  return x > 0.f ? x : expm1f(x);
}

__device__ __forceinline__ float bf2f(unsigned short u) {
  union { unsigned int i; float f; } c;
  c.i = (unsigned int)u << 16;
  return c.f;
}

__device__ __forceinline__ float2 bfpair(unsigned int d) {
  union { unsigned int i; float f; } a, b;
  a.i = d << 16;
  b.i = d & 0xffff0000u;
  return make_float2(a.f, b.f);
}

__device__ __forceinline__ unsigned int packbf(float x, float y) {
  union { __hip_bfloat162 v; unsigned int u; } c;
  c.v = __float22bfloat162_rn(make_float2(x, y));
  return c.u;
}

// ---------------- graph preprocessing ----------------
__global__ void zero_pre() {
  int i = blockIdx.x * blockDim.x + threadIdx.x;
  if (i < NN) { g_cnt[i] = 0; g_cursor[i] = 0; }
  if (i < CC * DD) g_sums[i] = 0.f;
  if (i < CC) g_cntf[i] = 0.f;
}

__global__ void hist_k(const int* __restrict__ dst) {
  int e = blockIdx.x * blockDim.x + threadIdx.x;
  if (e < EE) atomicAdd(&g_cnt[dst[e]], 1);
}

__global__ void scan_k() {
  __shared__ int part[1024];
  int t = threadIdx.x;
  int base = t * 20;
  int s = 0;
#pragma unroll
  for (int j = 0; j < 20; ++j) { int i = base + j; if (i < NN) s += g_cnt[i]; }
  part[t] = s;
  __syncthreads();
  for (int off = 1; off < 1024; off <<= 1) {
    int v = (t >= off) ? part[t - off] : 0;
    __syncthreads();
    part[t] += v;
    __syncthreads();
  }
  int run = (t > 0) ? part[t - 1] : 0;
#pragma unroll
  for (int j = 0; j < 20; ++j) {
    int i = base + j;
    if (i < NN) {
      g_rowstart[i] = run;
      int c = g_cnt[i];
      run += c;
      float dg = (float)(c + 1);
      g_invdeg[i] = 1.0f / dg;
      g_dinv[i] = 1.0f / sqrtf(dg);
    }
  }
  if (t == 1023) g_rowstart[NN] = run;
}

__global__ void fill_k(const int* __restrict__ src, const int* __restrict__ dst) {
  int e = blockIdx.x * blockDim.x + threadIdx.x;
  if (e < EE) {
    int d = dst[e];
    int p = atomicAdd(&g_cursor[d], 1);
    int j = g_rowstart[d] + p;
    int si = src[e];
    float coef = g_dinv[si] * g_dinv[d];
    g_edge[j] = make_int2(si, __float_as_int(coef));
  }
}

// x fp32 -> bf16
__global__ __launch_bounds__(256) void cvt_k(const float* __restrict__ x,
                                             unsigned short* __restrict__ xb) {
  int i = blockIdx.x * blockDim.x + threadIdx.x;  // 8 elems per thread
  const float4* x4 = (const float4*)x;
  float4 a = x4[i * 2], b = x4[i * 2 + 1];
  uint4 o;
  o.x = packbf(a.x, a.y);
  o.y = packbf(a.z, a.w);
  o.z = packbf(b.x, b.y);
  o.w = packbf(b.z, b.w);
  ((uint4*)xb)[i] = o;
}

// ---------------- weight transpose + bf16 split ----------------
struct WPtrs { const float* p[12]; };

__global__ __launch_bounds__(256) void wprep_k(WPtrs wp) {
  __shared__ float t[64][65];
  int widx = blockIdx.z;
  int kt0 = blockIdx.x * 64, nt0 = blockIdx.y * 64;
  const float* W = wp.p[widx];
  int tid = threadIdx.x;
  int ln = tid & 63, lk = tid >> 6;
  for (int kk = lk; kk < 64; kk += 4)
    t[kk][ln] = W[(size_t)(kt0 + kk) * DD + nt0 + ln];
  __syncthreads();
  for (int nn = lk; nn < 64; nn += 4) {
    float v = t[ln][nn];
    __hip_bfloat16 hb = __float2bfloat16(v);
    float hf = __bfloat162float(hb);
    __hip_bfloat16 lb = __float2bfloat16(v - hf);
    union { __hip_bfloat16 b; unsigned short s; } ch, cl;
    ch.b = hb; cl.b = lb;
    size_t o = (size_t)widx * DD * DD + (size_t)(nt0 + nn) * DD + kt0 + ln;
    g_wT1[o] = ch.s;
    g_wT2[o] = cl.s;
  }
}

// ---------------- MFMA GEMM: C[20000,256] = epi(A @ W), bf16 acts, split-B ------
// EPI 0: C = acc ; EPI 1: C = elu(alpha*acc+bias) ; EPI 2: C = (acc+bias)*mul
template <int EPI>
__global__ __launch_bounds__(256) void gemm_k(const unsigned short* __restrict__ A,
                                              const unsigned short* __restrict__ B1,
                                              const unsigned short* __restrict__ B2,
                                              unsigned short* __restrict__ C,
                                              const float* __restrict__ bias,
                                              const float* __restrict__ alphap,
                                              const unsigned short* __restrict__ mul) {
  __shared__ float ct[64][68];
  // bijective chunked XCD swizzle over 1252 blocks (157,157,157,157,156,156,156,156)
  int b = blockIdx.x;
  int xcd = b & 7, off = b >> 3;
  int logical = (xcd < 4) ? xcd * 157 + off : 628 + (xcd - 4) * 156 + off;
  int mblk = logical >> 2, nblk = logical & 3;

  int tid = threadIdx.x;
  int wave = tid >> 6, lane = tid & 63;
  int wm = wave >> 1, wn = wave & 1;
  int lr = lane & 15, lk = lane >> 4;
  int row0 = mblk * 64, col0 = nblk * 64;
  int arow = row0 + wm * 32 + lr;
  int bcol = col0 + wn * 32 + lr;

  f4v acc[2][2];
#pragma unroll
  for (int i = 0; i < 2; ++i)
#pragma unroll
    for (int j = 0; j < 2; ++j) acc[i][j] = (f4v){0.f, 0.f, 0.f, 0.f};

#pragma unroll
  for (int kt = 0; kt < DD; kt += 32) {
    int ko = kt + lk * 8;
    s8v a[2], b1v[2], b2v[2];
#pragma unroll
    for (int mi = 0; mi < 2; ++mi) {
      int r = arow + mi * 16;
      r = r < NN ? r : NN - 1;
      a[mi] = *(const s8v*)(A + (size_t)r * DD + ko);
    }
#pragma unroll
    for (int nj = 0; nj < 2; ++nj) {
      size_t o = (size_t)(bcol + nj * 16) * DD + ko;
      b1v[nj] = *(const s8v*)(B1 + o);
      b2v[nj] = *(const s8v*)(B2 + o);
    }
#pragma unroll
    for (int mi = 0; mi < 2; ++mi)
#pragma unroll
      for (int nj = 0; nj < 2; ++nj) {
        acc[mi][nj] = __builtin_amdgcn_mfma_f32_16x16x32_bf16(a[mi], b1v[nj], acc[mi][nj], 0, 0, 0);
        acc[mi][nj] = __builtin_amdgcn_mfma_f32_16x16x32_bf16(a[mi], b2v[nj], acc[mi][nj], 0, 0, 0);
      }
  }

  // frags -> LDS (fp32)
#pragma unroll
  for (int mi = 0; mi < 2; ++mi)
#pragma unroll
    for (int nj = 0; nj < 2; ++nj)
#pragma unroll
      for (int r = 0; r < 4; ++r)
        ct[wm * 32 + mi * 16 + lk * 4 + r][wn * 32 + nj * 16 + lr] = acc[mi][nj][r];
  __syncthreads();

  float alpha = 1.f;
  if (EPI == 1) alpha = alphap ? *alphap : 1.f;

  // readout: full-line bf16 stores (8 lanes x 16B = 128B per row)
#pragma unroll
  for (int p = 0; p < 2; ++p) {
    int row = p * 32 + (tid >> 3);
    int c0 = (tid & 7) * 8;
    int gr = row0 + row;
    int gc = col0 + c0;
    float v[8];
    float4 va = *(float4*)&ct[row][c0];
    float4 vb = *(float4*)&ct[row][c0 + 4];
    v[0] = va.x; v[1] = va.y; v[2] = va.z; v[3] = va.w;
    v[4] = vb.x; v[5] = vb.y; v[6] = vb.z; v[7] = vb.w;
    if (gr < NN) {
      if (EPI == 1) {
        float4 bv0 = *(const float4*)(bias + gc);
        float4 bv1 = *(const float4*)(bias + gc + 4);
        float bb[8] = {bv0.x, bv0.y, bv0.z, bv0.w, bv1.x, bv1.y, bv1.z, bv1.w};
#pragma unroll
        for (int i = 0; i < 8; ++i) v[i] = eluf(fmaf(alpha, v[i], bb[i]));
      } else if (EPI == 2) {
        float4 bv0 = *(const float4*)(bias + gc);
        float4 bv1 = *(const float4*)(bias + gc + 4);
        float bb[8] = {bv0.x, bv0.y, bv0.z, bv0.w, bv1.x, bv1.y, bv1.z, bv1.w};
        uint4 mu = *(const uint4*)(mul + (size_t)gr * DD + gc);
        float2 m0 = bfpair(mu.x), m1 = bfpair(mu.y), m2 = bfpair(mu.z), m3 = bfpair(mu.w);
        float mm[8] = {m0.x, m0.y, m1.x, m1.y, m2.x, m2.y, m3.x, m3.y};
#pragma unroll
        for (int i = 0; i < 8; ++i) v[i] = (v[i] + bb[i]) * mm[i];
      }
      uint4 o;
      o.x = packbf(v[0], v[1]);
      o.y = packbf(v[2], v[3]);
      o.z = packbf(v[4], v[5]);
      o.w = packbf(v[6], v[7]);
      *(uint4*)(C + (size_t)gr * DD + gc) = o;
    }
  }
}

// ---------------- CSR aggregation (bf16 rows, fp32 accum) ----------------
template <int RES>
__device__ __forceinline__ float4 agg_row_b(int row, int lane,
                                            const unsigned short* __restrict__ h,
                                            const float* __restrict__ bias,
                                            const unsigned short* __restrict__ res) {
  const uint2* h2 = (const uint2*)h;
  float4 a = make_float4(0.f, 0.f, 0.f, 0.f);
  int s = g_rowstart[row], e = g_rowstart[row + 1];
  int j = s;
  for (; j + 16 <= e; j += 16) {
    int2 E[16];
    uint2 v[16];
#pragma unroll
    for (int u = 0; u < 16; ++u) E[u] = g_edge[j + u];
#pragma unroll
    for (int u = 0; u < 16; ++u) v[u] = h2[(size_t)E[u].x * 64 + lane];
#pragma unroll
    for (int u = 0; u < 16; ++u) {
      float c = __int_as_float(E[u].y);
      float2 p0 = bfpair(v[u].x), p1 = bfpair(v[u].y);
      a.x = fmaf(c, p0.x, a.x); a.y = fmaf(c, p0.y, a.y);
      a.z = fmaf(c, p1.x, a.z); a.w = fmaf(c, p1.y, a.w);
    }
  }
  for (; j + 4 <= e; j += 4) {
    int2 E[4];
    uint2 v[4];
#pragma unroll
    for (int u = 0; u < 4; ++u) E[u] = g_edge[j + u];
#pragma unroll
    for (int u = 0; u < 4; ++u) v[u] = h2[(size_t)E[u].x * 64 + lane];
#pragma unroll
    for (int u = 0; u < 4; ++u) {
      float c = __int_as_float(E[u].y);
      float2 p0 = bfpair(v[u].x), p1 = bfpair(v[u].y);
      a.x = fmaf(c, p0.x, a.x); a.y = fmaf(c, p0.y, a.y);
      a.z = fmaf(c, p1.x, a.z); a.w = fmaf(c, p1.y, a.w);
    }
  }
  for (; j < e; ++j) {
    int2 E0 = g_edge[j];
    uint2 v0 = h2[(size_t)E0.x * 64 + lane];
    float c = __int_as_float(E0.y);
    float2 p0 = bfpair(v0.x), p1 = bfpair(v0.y);
    a.x = fmaf(c, p0.x, a.x); a.y = fmaf(c, p0.y, a.y);
    a.z = fmaf(c, p1.x, a.z); a.w = fmaf(c, p1.y, a.w);
  }
  float idg = g_invdeg[row];
  uint2 hv = h2[(size_t)row * 64 + lane];
  float2 h0 = bfpair(hv.x), h1 = bfpair(hv.y);
  float4 bv = ((const float4*)bias)[lane];
  float4 o;
  o.x = a.x + h0.x * idg + bv.x;
  o.y = a.y + h0.y * idg + bv.y;
  o.z = a.z + h1.x * idg + bv.z;
  o.w = a.w + h1.y * idg + bv.w;
  if (RES) {
    uint2 rv = ((const uint2*)res)[(size_t)row * 64 + lane];
    float2 r0 = bfpair(rv.x), r1 = bfpair(rv.y);
    o.x += r0.x; o.y += r0.y; o.z += r1.x; o.w += r1.y;
  }
  return o;
}

template <int ELU, int RES>
__global__ __launch_bounds__(256) void agg_k(const unsigned short* __restrict__ h,
                                             const float* __restrict__ bias,
                                             const unsigned short* __restrict__ res,
                                             unsigned short* __restrict__ out) {
  int wid = (blockIdx.x * 256 + threadIdx.x) >> 6;  // 10000 waves, 2 rows each
  int lane = threadIdx.x & 63;
#pragma unroll
  for (int rr = 0; rr < 2; ++rr) {
    int row = wid + rr * 10000;
    float4 o = agg_row_b<RES>(row, lane, h, bias, res);
    if (ELU) {
      o.x = eluf(o.x); o.y = eluf(o.y); o.z = eluf(o.z); o.w = eluf(o.w);
    }
    ((uint2*)out)[(size_t)row * 64 + lane] = make_uint2(packbf(o.x, o.y), packbf(o.z, o.w));
  }
}

// final layer: agg + ELU + prompt attention fused
__global__ __launch_bounds__(256) void aggattn_k(const unsigned short* __restrict__ h,
                                                 const float* __restrict__ bias,
                                                 const float* __restrict__ aW,
                                                 const float* __restrict__ ab,
                                                 const float* __restrict__ plist,
                                                 unsigned short* __restrict__ out) {
  int wid = (blockIdx.x * 256 + threadIdx.x) >> 6;
  int lane = threadIdx.x & 63;
#pragma unroll
  for (int rr = 0; rr < 2; ++rr) {
    int row = wid + rr * 10000;
    float4 o = agg_row_b<0>(row, lane, h, bias, nullptr);
    o.x = eluf(o.x); o.y = eluf(o.y); o.z = eluf(o.z); o.w = eluf(o.w);
    int d = lane * 4;
    float lg[5];
#pragma unroll
    for (int k = 0; k < 5; ++k) {
      float p = o.x * aW[(d + 0) * 5 + k] + o.y * aW[(d + 1) * 5 + k] +
                o.z * aW[(d + 2) * 5 + k] + o.w * aW[(d + 3) * 5 + k];
      lg[k] = wave_sum(p) + ab[k];
    }
    float mx = lg[0];
#pragma unroll
    for (int k = 1; k < 5; ++k) mx = fmaxf(mx, lg[k]);
    float w[5], sum = 0.f;
#pragma unroll
    for (int k = 0; k < 5; ++k) { w[k] = expf(lg[k] - mx); sum += w[k]; }
    float inv = 1.f / sum;
#pragma unroll
    for (int k = 0; k < 5; ++k) {
      float wk = w[k] * inv;
      float4 pv = ((const float4*)plist)[k * 64 + lane];
      o.x = fmaf(wk, pv.x, o.x);
      o.y = fmaf(wk, pv.y, o.y);
      o.z = fmaf(wk, pv.z, o.z);
      o.w = fmaf(wk, pv.w, o.w);
    }
    ((uint2*)out)[(size_t)row * 64 + lane] = make_uint2(packbf(o.x, o.y), packbf(o.z, o.w));
  }
}

// ---------------- class prototypes: LDS column-owned partials ----------------
__global__ __launch_bounds__(256) void proto_k(const unsigned short* __restrict__ embed,
                                               const int* __restrict__ idxp,
                                               const int* __restrict__ labels) {
  __shared__ float sums[CC][DD];
  __shared__ float cnts[CC];
  int t = threadIdx.x;
#pragma unroll
  for (int c = 0; c < CC; ++c) sums[c][t] = 0.f;
  if (t < CC) cnts[t] = 0.f;
  __syncthreads();
  int m0 = blockIdx.x * 32;
  for (int r0 = 0; r0 < 32; r0 += 4) {
    int i4[4], l4[4];
    float v[4];
#pragma unroll
    for (int u = 0; u < 4; ++u) {
      int m = m0 + r0 + u;
      i4[u] = idxp[m];
      l4[u] = labels[m];
    }
#pragma unroll
    for (int u = 0; u < 4; ++u) v[u] = bf2f(embed[(size_t)i4[u] * DD + t]);
#pragma unroll
    for (int u = 0; u < 4; ++u) sums[l4[u]][t] += v[u];
    if (t == 0) {
#pragma unroll
      for (int u = 0; u < 4; ++u) cnts[l4[u]] += 1.f;
    }
  }
  __syncthreads();
#pragma unroll
  for (int c = 0; c < CC; ++c) atomicAdd(&g_sums[c * DD + t], sums[c][t]);
  if (t < CC) atomicAdd(&g_cntf[t], cnts[t]);
}

__global__ void protonorm_k() {
  __shared__ float red[4];
  int t = threadIdx.x;
  int lane = t & 63, w = t >> 6;
  for (int c = 0; c < CC; ++c) {
    float v = g_sums[c * DD + t] / fmaxf(g_cntf[c], 1.0f);
    float sq = wave_sum(v * v);
    if (lane == 0) red[w] = sq;
    __syncthreads();
    float tot = red[0] + red[1] + red[2] + red[3];
    float nrm = fmaxf(sqrtf(tot), 1e-8f);
    g_an[c * DD + t] = v / nrm;
    __syncthreads();
  }
}

// ---------------- cosine similarity + softmax ----------------
__global__ __launch_bounds__(256) void cos_k(const unsigned short* __restrict__ embed,
                                             const int* __restrict__ idxp,
                                             float* __restrict__ out) {
  int wid = (blockIdx.x * 256 + threadIdx.x) >> 6;
  int lane = threadIdx.x & 63;
  if (wid >= MM) return;
  int row = idxp[wid];
  uint2 rv = ((const uint2*)embed)[(size_t)row * 64 + lane];
  float2 r0 = bfpair(rv.x), r1 = bfpair(rv.y);
  float4 r = make_float4(r0.x, r0.y, r1.x, r1.y);
  float n = wave_sum(r.x * r.x + r.y * r.y + r.z * r.z + r.w * r.w);
  float rnf = 1.0f / fmaxf(sqrtf(n), 1e-8f);
  float lg[CC];
#pragma unroll
  for (int c = 0; c < CC; ++c) {
    float4 a = ((const float4*)g_an)[c * 64 + lane];
    float p = r.x * a.x + r.y * a.y + r.z * a.z + r.w * a.w;
    lg[c] = wave_sum(p) * rnf;
  }
  float mx = lg[0];
#pragma unroll
  for (int c = 1; c < CC; ++c) mx = fmaxf(mx, lg[c]);
  float s = 0.f, w[CC];
#pragma unroll
  for (int c = 0; c < CC; ++c) { w[c] = expf(lg[c] - mx); s += w[c]; }
  float inv = 1.f / s;
#pragma unroll
  for (int c = 0; c < CC; ++c)
    if (lane == c) out[(size_t)wid * CC + c] = w[c] * inv;
}

// ---------------- host orchestration ----------------
extern "C" void kernel_launch(void* const* d_in, const int* in_sizes, int n_in,
                              void* d_out, int out_size, void* d_ws, size_t ws_size,
                              hipStream_t stream) {
  (void)in_sizes; (void)n_in; (void)d_ws; (void)ws_size; (void)out_size;
  const float* x      = (const float*)d_in[0];
  const int*   src    = (const int*)d_in[1];
  const int*   dst    = (const int*)d_in[2];
  const int*   idx    = (const int*)d_in[3];
  const int*   labels = (const int*)d_in[4];
  const float* W1 = (const float*)d_in[6];
  const float* b1 = (const float*)d_in[7];
  const float* W2 = (const float*)d_in[8];
  const float* b2 = (const float*)d_in[9];
  const float* W3 = (const float*)d_in[10];
  const float* b3 = (const float*)d_in[11];
  const float* cw_in  = (const float*)d_in[12];
  const float* cb_in  = (const float*)d_in[13];
  const float* cw_hid = (const float*)d_in[14];
  const float* cb_hid = (const float*)d_in[15];
  const float* cw_out = (const float*)d_in[16];
  const float* cb_out = (const float*)d_in[17];
  const float* plist  = (const float*)d_in[18];
  const float* aW     = (const float*)d_in[19];
  const float* ab     = (const float*)d_in[20];
  const float* w2s    = (const float*)d_in[21];
  float* out = (float*)d_out;

  unsigned short *xb, *xo, *hb, *e1b, *e2b, *wt1, *wt2;
  hipGetSymbolAddress((void**)&xb,  HIP_SYMBOL(g_xb));
  hipGetSymbolAddress((void**)&xo,  HIP_SYMBOL(g_xo));
  hipGetSymbolAddress((void**)&hb,  HIP_SYMBOL(g_hb));
  hipGetSymbolAddress((void**)&e1b, HIP_SYMBOL(g_e1b));
  hipGetSymbolAddress((void**)&e2b, HIP_SYMBOL(g_e2b));
  hipGetSymbolAddress((void**)&wt1, HIP_SYMBOL(g_wT1));
  hipGetSymbolAddress((void**)&wt2, HIP_SYMBOL(g_wT2));

  auto WT1 = [&](int w) { return (const unsigned short*)(wt1 + (size_t)w * DD * DD); };
  auto WT2 = [&](int w) { return (const unsigned short*)(wt2 + (size_t)w * DD * DD); };

  // preprocessing
  zero_pre<<<79, 256, 0, stream>>>();
  hist_k<<<1250, 256, 0, stream>>>(dst);
  scan_k<<<1, 1024, 0, stream>>>();
  fill_k<<<1250, 256, 0, stream>>>(src, dst);
  cvt_k<<<2500, 256, 0, stream>>>(x, xb);

  WPtrs wp;
  wp.p[0] = W1; wp.p[1] = W2; wp.p[2] = W3;
  for (int t = 0; t < 3; ++t) {
    wp.p[3 + t] = cw_in  + (size_t)t * DD * DD;
    wp.p[6 + t] = cw_hid + (size_t)t * DD * DD;
    wp.p[9 + t] = cw_out + (size_t)t * DD * DD;
  }
  wprep_k<<<dim3(4, 4, 12), 256, 0, stream>>>(wp);

  const int GG = 1252;  // 313 mblk x 4 nblk
  // think layers (e3 dead: gcn_weight1 = gcn_weight3 = 0)
  const unsigned short* xin = xb;
  for (int t = 0; t < TT; ++t) {
    gemm_k<0><<<GG, 256, 0, stream>>>(xin, WT1(0), WT2(0), hb, nullptr, nullptr, nullptr);
    agg_k<0, 0><<<2500, 256, 0, stream>>>(hb, b1, nullptr, e1b);
    gemm_k<0><<<GG, 256, 0, stream>>>(e1b, WT1(1), WT2(1), hb, nullptr, nullptr, nullptr);
    agg_k<0, 1><<<2500, 256, 0, stream>>>(hb, b2, e1b, e2b);
    gemm_k<1><<<GG, 256, 0, stream>>>(e2b, WT1(3 + t), WT2(3 + t), e1b,
                                      cb_in + (size_t)t * DD, w2s, nullptr);
    gemm_k<1><<<GG, 256, 0, stream>>>(e1b, WT1(6 + t), WT2(6 + t), hb,
                                      cb_hid + (size_t)t * DD, nullptr, nullptr);
    gemm_k<2><<<GG, 256, 0, stream>>>(hb, WT1(9 + t), WT2(9 + t), xo,
                                      cb_out + (size_t)t * DD, nullptr, xb);
    xin = xo;
  }

  // final GCN with ELU; last layer fuses prompt attention
  gemm_k<0><<<GG, 256, 0, stream>>>(xin, WT1(0), WT2(0), hb, nullptr, nullptr, nullptr);
  agg_k<1, 0><<<2500, 256, 0, stream>>>(hb, b1, nullptr, e1b);
  gemm_k<0><<<GG, 256, 0, stream>>>(e1b, WT1(1), WT2(1), hb, nullptr, nullptr, nullptr);
  agg_k<1, 0><<<2500, 256, 0, stream>>>(hb, b2, nullptr, e2b);
  gemm_k<0><<<GG, 256, 0, stream>>>(e2b, WT1(2), WT2(2), hb, nullptr, nullptr, nullptr);
  aggattn_k<<<2500, 256, 0, stream>>>(hb, b3, aW, ab, plist, e2b);

  // prototypes + cosine softmax
  proto_k<<<64, 256, 0, stream>>>(e2b, idx, labels);
  protonorm_k<<<1, 256, 0, stream>>>();
  cos_k<<<512, 256, 0, stream>>>(e2b, idx, out);
}

// Round 5
// 728.053 us; speedup vs baseline: 2.0446x; 1.3241x over previous
//
#include <hip/hip_runtime.h>
#include <hip/hip_bf16.h>
#include <math.h>

#define NN 20000
#define DD 256
#define EE 320000
#define MM 2048
#define CC 10
#define TT 3

typedef __attribute__((ext_vector_type(8))) short s8v;
typedef __attribute__((ext_vector_type(4))) float f4v;

// ---------------- device global scratch ----------------
__device__ unsigned short g_xb[NN * DD];   // bf16 original x
__device__ unsigned short g_xo[NN * DD];   // bf16 evolving x
__device__ unsigned short g_hb[NN * DD];
__device__ unsigned short g_e1b[NN * DD];
__device__ unsigned short g_e2b[NN * DD];
__device__ int   g_cnt[NN];
__device__ int   g_cursor[NN];
__device__ int   g_rowstart[NN + 1];
__device__ float g_dinv[NN];
__device__ float g_invdeg[NN];
__device__ int   g_part[128];
__device__ int2  g_edge[EE];     // {src, coef bits} in dst-CSR order
__device__ float g_sums[CC * DD];
__device__ float g_cntf[CC];
__device__ float g_an[CC * DD];
// transposed + split weights: wT[n][k], 12 matrices of 256x256 bf16 (hi, lo)
__device__ unsigned short g_wT1[12 * DD * DD];
__device__ unsigned short g_wT2[12 * DD * DD];

__device__ __forceinline__ float wave_sum(float v) {
#pragma unroll
  for (int off = 32; off > 0; off >>= 1) v += __shfl_xor(v, off);
  return v;
}

__device__ __forceinline__ float eluf(float x) {
  return x > 0.f ? x : expm1f(x);
}

__device__ __forceinline__ float bf2f(unsigned short u) {
  union { unsigned int i; float f; } c;
  c.i = (unsigned int)u << 16;
  return c.f;
}

__device__ __forceinline__ float2 bfpair(unsigned int d) {
  union { unsigned int i; float f; } a, b;
  a.i = d << 16;
  b.i = d & 0xffff0000u;
  return make_float2(a.f, b.f);
}

__device__ __forceinline__ unsigned int packbf(float x, float y) {
  union { __hip_bfloat162 v; unsigned int u; } c;
  c.v = __float22bfloat162_rn(make_float2(x, y));
  return c.u;
}

// async 16B global -> LDS (no VGPR cost for in-flight data)
__device__ __forceinline__ void gl_lds16(const unsigned short* g, unsigned short* l) {
  __builtin_amdgcn_global_load_lds(
      (const __attribute__((address_space(1))) unsigned int*)g,
      (__attribute__((address_space(3))) unsigned int*)l, 16, 0, 0);
}

// ---------------- graph preprocessing ----------------
__global__ void zero_pre() {
  int i = blockIdx.x * blockDim.x + threadIdx.x;
  if (i < NN) { g_cnt[i] = 0; g_cursor[i] = 0; }
  if (i < CC * DD) g_sums[i] = 0.f;
  if (i < CC) g_cntf[i] = 0.f;
}

__global__ void hist_k(const int* __restrict__ dst) {
  int e = blockIdx.x * blockDim.x + threadIdx.x;
  if (e < EE) atomicAdd(&g_cnt[dst[e]], 1);
}

// hierarchical scan: A) per-block sums, B) scan of 79 partials, C) local scans
__global__ __launch_bounds__(256) void scanA_k() {
  __shared__ int s[256];
  int t = threadIdx.x;
  int i = blockIdx.x * 256 + t;
  int v = (i < NN) ? g_cnt[i] : 0;
  s[t] = v;
  __syncthreads();
#pragma unroll
  for (int off = 128; off > 0; off >>= 1) {
    if (t < off) s[t] += s[t + off];
    __syncthreads();
  }
  if (t == 0) g_part[blockIdx.x] = s[0];
}

__global__ __launch_bounds__(128) void scanB_k() {
  __shared__ int s[128];
  int t = threadIdx.x;
  int p = (t < 79) ? g_part[t] : 0;
  s[t] = p;
  __syncthreads();
#pragma unroll
  for (int off = 1; off < 128; off <<= 1) {
    int v = (t >= off) ? s[t - off] : 0;
    __syncthreads();
    s[t] += v;
    __syncthreads();
  }
  g_part[t] = s[t] - p;  // exclusive
  if (t == 0) g_rowstart[NN] = EE;
}

__global__ __launch_bounds__(256) void scanC_k() {
  __shared__ int s[256];
  int t = threadIdx.x;
  int i = blockIdx.x * 256 + t;
  int v = (i < NN) ? g_cnt[i] : 0;
  s[t] = v;
  __syncthreads();
#pragma unroll
  for (int off = 1; off < 256; off <<= 1) {
    int x = (t >= off) ? s[t - off] : 0;
    __syncthreads();
    s[t] += x;
    __syncthreads();
  }
  if (i < NN) {
    g_rowstart[i] = g_part[blockIdx.x] + s[t] - v;
    float dg = (float)(v + 1);
    g_invdeg[i] = 1.0f / dg;
    g_dinv[i] = 1.0f / sqrtf(dg);
  }
}

__global__ void fill_k(const int* __restrict__ src, const int* __restrict__ dst) {
  int e = blockIdx.x * blockDim.x + threadIdx.x;
  if (e < EE) {
    int d = dst[e];
    int p = atomicAdd(&g_cursor[d], 1);
    int j = g_rowstart[d] + p;
    int si = src[e];
    float coef = g_dinv[si] * g_dinv[d];
    g_edge[j] = make_int2(si, __float_as_int(coef));
  }
}

// x fp32 -> bf16
__global__ __launch_bounds__(256) void cvt_k(const float* __restrict__ x,
                                             unsigned short* __restrict__ xb) {
  int i = blockIdx.x * blockDim.x + threadIdx.x;
  const float4* x4 = (const float4*)x;
  float4 a = x4[i * 2], b = x4[i * 2 + 1];
  uint4 o;
  o.x = packbf(a.x, a.y);
  o.y = packbf(a.z, a.w);
  o.z = packbf(b.x, b.y);
  o.w = packbf(b.z, b.w);
  ((uint4*)xb)[i] = o;
}

// ---------------- weight transpose + bf16 split ----------------
struct WPtrs { const float* p[12]; };

__global__ __launch_bounds__(256) void wprep_k(WPtrs wp) {
  __shared__ float t[64][65];
  int widx = blockIdx.z;
  int kt0 = blockIdx.x * 64, nt0 = blockIdx.y * 64;
  const float* W = wp.p[widx];
  int tid = threadIdx.x;
  int ln = tid & 63, lk = tid >> 6;
  for (int kk = lk; kk < 64; kk += 4)
    t[kk][ln] = W[(size_t)(kt0 + kk) * DD + nt0 + ln];
  __syncthreads();
  for (int nn = lk; nn < 64; nn += 4) {
    float v = t[ln][nn];
    __hip_bfloat16 hb = __float2bfloat16(v);
    float hf = __bfloat162float(hb);
    __hip_bfloat16 lb = __float2bfloat16(v - hf);
    union { __hip_bfloat16 b; unsigned short s; } ch, cl;
    ch.b = hb; cl.b = lb;
    size_t o = (size_t)widx * DD * DD + (size_t)(nt0 + nn) * DD + kt0 + ln;
    g_wT1[o] = ch.s;
    g_wT2[o] = cl.s;
  }
}

// ---------------- MFMA GEMM with global_load_lds staging ----------------
// Tile 128x64, BK=64, 4 waves (2x2), wave frag grid 4mi x 2nj, split-B bf16x2.
// LDS chunks of 16B: [0,1024) = A (row,pos), [1024,1536) = B1 (col,pos),
// [1536,2048) = B2.  pos = kc ^ (row&7)  (XOR-swizzle, applied on the GLOBAL
// source address; LDS written linearly by global_load_lds).
union GemmSM {
  unsigned short st[2048 * 8];  // 32 KB staging
  float ct[128][68];            // 34816 B epilogue transpose buffer
};

template <int EPI>
__global__ __launch_bounds__(256) void gemm_k(const unsigned short* __restrict__ A,
                                              const unsigned short* __restrict__ B1,
                                              const unsigned short* __restrict__ B2,
                                              unsigned short* __restrict__ C,
                                              const float* __restrict__ bias,
                                              const float* __restrict__ alphap,
                                              const unsigned short* __restrict__ mul) {
  __shared__ GemmSM sm;
  // bijective chunked XCD swizzle over 628 blocks (79,79,79,79,78,78,78,78):
  // consecutive logical ids (one m-slice's 4 n-blocks) stay on one XCD.
  int b = blockIdx.x;
  int xcd = b & 7, off = b >> 3;
  int logical = (xcd < 4) ? xcd * 79 + off : 316 + (xcd - 4) * 78 + off;
  int mblk = logical >> 2, nblk = logical & 3;
  int row0 = mblk * 128, col0 = nblk * 64;

  int tid = threadIdx.x;
  int wv = tid >> 6, lane = tid & 63;
  int wm = wv >> 1, wn = wv & 1;
  int lr = lane & 15, lk = lane >> 4;

  f4v acc[4][2];
#pragma unroll
  for (int i = 0; i < 4; ++i)
#pragma unroll
    for (int j = 0; j < 2; ++j) acc[i][j] = (f4v){0.f, 0.f, 0.f, 0.f};

#pragma unroll
  for (int kt = 0; kt < DD; kt += 64) {
    // ---- stage: 2048 chunks, 8 wave-issues per wave ----
#pragma unroll
    for (int i = 0; i < 8; ++i) {
      int cb = (wv * 8 + i) * 64;        // wave-uniform chunk base
      int c = cb + lane;
      unsigned short* ldst = sm.st + (size_t)cb * 8;
      if (cb < 1024) {                   // A region
        int row = c >> 3, kc = c & 7;
        int gr = row0 + row;
        gr = gr < NN ? gr : NN - 1;
        gl_lds16(A + (size_t)gr * DD + kt + ((kc ^ (row & 7)) << 3), ldst);
      } else if (cb < 1536) {            // B1 region
        int c2 = c - 1024;
        int col = c2 >> 3, kc = c2 & 7;
        gl_lds16(B1 + (size_t)(col0 + col) * DD + kt + ((kc ^ (col & 7)) << 3), ldst);
      } else {                           // B2 region
        int c2 = c - 1536;
        int col = c2 >> 3, kc = c2 & 7;
        gl_lds16(B2 + (size_t)(col0 + col) * DD + kt + ((kc ^ (col & 7)) << 3), ldst);
      }
    }
    __syncthreads();  // drains vmcnt before barrier
    // ---- compute ----
#pragma unroll
    for (int ksub = 0; ksub < 2; ++ksub) {
      int kc = ksub * 4 + lk;
      s8v a[4], b1v[2], b2v[2];
#pragma unroll
      for (int mi = 0; mi < 4; ++mi) {
        int row = wm * 64 + mi * 16 + lr;
        a[mi] = *(const s8v*)(sm.st + (row * 8 + (kc ^ (row & 7))) * 8);
      }
#pragma unroll
      for (int nj = 0; nj < 2; ++nj) {
        int col = wn * 32 + nj * 16 + lr;
        int ch = col * 8 + (kc ^ (col & 7));
        b1v[nj] = *(const s8v*)(sm.st + 8192 + ch * 8);
        b2v[nj] = *(const s8v*)(sm.st + 12288 + ch * 8);
      }
#pragma unroll
      for (int mi = 0; mi < 4; ++mi)
#pragma unroll
        for (int nj = 0; nj < 2; ++nj) {
          acc[mi][nj] = __builtin_amdgcn_mfma_f32_16x16x32_bf16(a[mi], b1v[nj], acc[mi][nj], 0, 0, 0);
          acc[mi][nj] = __builtin_amdgcn_mfma_f32_16x16x32_bf16(a[mi], b2v[nj], acc[mi][nj], 0, 0, 0);
        }
    }
    __syncthreads();
  }

  // ---- epilogue: frags -> LDS fp32 -> full-line bf16 stores ----
#pragma unroll
  for (int mi = 0; mi < 4; ++mi)
#pragma unroll
    for (int nj = 0; nj < 2; ++nj)
#pragma unroll
      for (int r = 0; r < 4; ++r)
        sm.ct[wm * 64 + mi * 16 + lk * 4 + r][wn * 32 + nj * 16 + lr] = acc[mi][nj][r];
  __syncthreads();

  float alpha = 1.f;
  if (EPI == 1) alpha = alphap ? *alphap : 1.f;
#pragma unroll
  for (int p = 0; p < 4; ++p) {
    int row = p * 32 + (tid >> 3);
    int c0 = (tid & 7) * 8;
    int gr = row0 + row;
    int gc = col0 + c0;
    if (gr < NN) {
      float v[8];
      float4 va = *(float4*)&sm.ct[row][c0];
      float4 vb = *(float4*)&sm.ct[row][c0 + 4];
      v[0] = va.x; v[1] = va.y; v[2] = va.z; v[3] = va.w;
      v[4] = vb.x; v[5] = vb.y; v[6] = vb.z; v[7] = vb.w;
      if (EPI == 1) {
        float4 bv0 = *(const float4*)(bias + gc);
        float4 bv1 = *(const float4*)(bias + gc + 4);
        float bb[8] = {bv0.x, bv0.y, bv0.z, bv0.w, bv1.x, bv1.y, bv1.z, bv1.w};
#pragma unroll
        for (int i = 0; i < 8; ++i) v[i] = eluf(fmaf(alpha, v[i], bb[i]));
      } else if (EPI == 2) {
        float4 bv0 = *(const float4*)(bias + gc);
        float4 bv1 = *(const float4*)(bias + gc + 4);
        float bb[8] = {bv0.x, bv0.y, bv0.z, bv0.w, bv1.x, bv1.y, bv1.z, bv1.w};
        uint4 mu = *(const uint4*)(mul + (size_t)gr * DD + gc);
        float2 m0 = bfpair(mu.x), m1 = bfpair(mu.y), m2 = bfpair(mu.z), m3 = bfpair(mu.w);
        float mm[8] = {m0.x, m0.y, m1.x, m1.y, m2.x, m2.y, m3.x, m3.y};
#pragma unroll
        for (int i = 0; i < 8; ++i) v[i] = (v[i] + bb[i]) * mm[i];
      }
      uint4 o;
      o.x = packbf(v[0], v[1]);
      o.y = packbf(v[2], v[3]);
      o.z = packbf(v[4], v[5]);
      o.w = packbf(v[6], v[7]);
      *(uint4*)(C + (size_t)gr * DD + gc) = o;
    }
  }
}

// ---------------- CSR aggregation (bf16 rows, fp32 accum) ----------------
template <int RES>
__device__ __forceinline__ float4 agg_row_b(int row, int lane,
                                            const unsigned short* __restrict__ h,
                                            const float* __restrict__ bias,
                                            const unsigned short* __restrict__ res) {
  const uint2* h2 = (const uint2*)h;
  float4 a = make_float4(0.f, 0.f, 0.f, 0.f);
  int s = g_rowstart[row], e = g_rowstart[row + 1];
  int j = s;
  for (; j + 16 <= e; j += 16) {
    int2 E[16];
    uint2 v[16];
#pragma unroll
    for (int u = 0; u < 16; ++u) E[u] = g_edge[j + u];
#pragma unroll
    for (int u = 0; u < 16; ++u) v[u] = h2[(size_t)E[u].x * 64 + lane];
#pragma unroll
    for (int u = 0; u < 16; ++u) {
      float c = __int_as_float(E[u].y);
      float2 p0 = bfpair(v[u].x), p1 = bfpair(v[u].y);
      a.x = fmaf(c, p0.x, a.x); a.y = fmaf(c, p0.y, a.y);
      a.z = fmaf(c, p1.x, a.z); a.w = fmaf(c, p1.y, a.w);
    }
  }
  for (; j + 4 <= e; j += 4) {
    int2 E[4];
    uint2 v[4];
#pragma unroll
    for (int u = 0; u < 4; ++u) E[u] = g_edge[j + u];
#pragma unroll
    for (int u = 0; u < 4; ++u) v[u] = h2[(size_t)E[u].x * 64 + lane];
#pragma unroll
    for (int u = 0; u < 4; ++u) {
      float c = __int_as_float(E[u].y);
      float2 p0 = bfpair(v[u].x), p1 = bfpair(v[u].y);
      a.x = fmaf(c, p0.x, a.x); a.y = fmaf(c, p0.y, a.y);
      a.z = fmaf(c, p1.x, a.z); a.w = fmaf(c, p1.y, a.w);
    }
  }
  for (; j < e; ++j) {
    int2 E0 = g_edge[j];
    uint2 v0 = h2[(size_t)E0.x * 64 + lane];
    float c = __int_as_float(E0.y);
    float2 p0 = bfpair(v0.x), p1 = bfpair(v0.y);
    a.x = fmaf(c, p0.x, a.x); a.y = fmaf(c, p0.y, a.y);
    a.z = fmaf(c, p1.x, a.z); a.w = fmaf(c, p1.y, a.w);
  }
  float idg = g_invdeg[row];
  uint2 hv = h2[(size_t)row * 64 + lane];
  float2 h0 = bfpair(hv.x), h1 = bfpair(hv.y);
  float4 bv = ((const float4*)bias)[lane];
  float4 o;
  o.x = a.x + h0.x * idg + bv.x;
  o.y = a.y + h0.y * idg + bv.y;
  o.z = a.z + h1.x * idg + bv.z;
  o.w = a.w + h1.y * idg + bv.w;
  if (RES) {
    uint2 rv = ((const uint2*)res)[(size_t)row * 64 + lane];
    float2 r0 = bfpair(rv.x), r1 = bfpair(rv.y);
    o.x += r0.x; o.y += r0.y; o.z += r1.x; o.w += r1.y;
  }
  return o;
}

template <int ELU, int RES>
__global__ __launch_bounds__(256) void agg_k(const unsigned short* __restrict__ h,
                                             const float* __restrict__ bias,
                                             const unsigned short* __restrict__ res,
                                             unsigned short* __restrict__ out) {
  int wid = (blockIdx.x * 256 + threadIdx.x) >> 6;
  int lane = threadIdx.x & 63;
#pragma unroll
  for (int rr = 0; rr < 2; ++rr) {
    int row = wid + rr * 10000;
    float4 o = agg_row_b<RES>(row, lane, h, bias, res);
    if (ELU) {
      o.x = eluf(o.x); o.y = eluf(o.y); o.z = eluf(o.z); o.w = eluf(o.w);
    }
    ((uint2*)out)[(size_t)row * 64 + lane] = make_uint2(packbf(o.x, o.y), packbf(o.z, o.w));
  }
}

// final layer: agg + ELU + prompt attention fused
__global__ __launch_bounds__(256) void aggattn_k(const unsigned short* __restrict__ h,
                                                 const float* __restrict__ bias,
                                                 const float* __restrict__ aW,
                                                 const float* __restrict__ ab,
                                                 const float* __restrict__ plist,
                                                 unsigned short* __restrict__ out) {
  int wid = (blockIdx.x * 256 + threadIdx.x) >> 6;
  int lane = threadIdx.x & 63;
#pragma unroll
  for (int rr = 0; rr < 2; ++rr) {
    int row = wid + rr * 10000;
    float4 o = agg_row_b<0>(row, lane, h, bias, nullptr);
    o.x = eluf(o.x); o.y = eluf(o.y); o.z = eluf(o.z); o.w = eluf(o.w);
    int d = lane * 4;
    float lg[5];
#pragma unroll
    for (int k = 0; k < 5; ++k) {
      float p = o.x * aW[(d + 0) * 5 + k] + o.y * aW[(d + 1) * 5 + k] +
                o.z * aW[(d + 2) * 5 + k] + o.w * aW[(d + 3) * 5 + k];
      lg[k] = wave_sum(p) + ab[k];
    }
    float mx = lg[0];
#pragma unroll
    for (int k = 1; k < 5; ++k) mx = fmaxf(mx, lg[k]);
    float w[5], sum = 0.f;
#pragma unroll
    for (int k = 0; k < 5; ++k) { w[k] = expf(lg[k] - mx); sum += w[k]; }
    float inv = 1.f / sum;
#pragma unroll
    for (int k = 0; k < 5; ++k) {
      float wk = w[k] * inv;
      float4 pv = ((const float4*)plist)[k * 64 + lane];
      o.x = fmaf(wk, pv.x, o.x);
      o.y = fmaf(wk, pv.y, o.y);
      o.z = fmaf(wk, pv.z, o.z);
      o.w = fmaf(wk, pv.w, o.w);
    }
    ((uint2*)out)[(size_t)row * 64 + lane] = make_uint2(packbf(o.x, o.y), packbf(o.z, o.w));
  }
}

// ---------------- class prototypes ----------------
__global__ __launch_bounds__(256) void proto_k(const unsigned short* __restrict__ embed,
                                               const int* __restrict__ idxp,
                                               const int* __restrict__ labels) {
  __shared__ float sums[CC][DD];
  __shared__ float cnts[CC];
  int t = threadIdx.x;
#pragma unroll
  for (int c = 0; c < CC; ++c) sums[c][t] = 0.f;
  if (t < CC) cnts[t] = 0.f;
  __syncthreads();
  int m0 = blockIdx.x * 32;
  for (int r0 = 0; r0 < 32; r0 += 4) {
    int i4[4], l4[4];
    float v[4];
#pragma unroll
    for (int u = 0; u < 4; ++u) {
      int m = m0 + r0 + u;
      i4[u] = idxp[m];
      l4[u] = labels[m];
    }
#pragma unroll
    for (int u = 0; u < 4; ++u) v[u] = bf2f(embed[(size_t)i4[u] * DD + t]);
#pragma unroll
    for (int u = 0; u < 4; ++u) sums[l4[u]][t] += v[u];
    if (t == 0) {
#pragma unroll
      for (int u = 0; u < 4; ++u) cnts[l4[u]] += 1.f;
    }
  }
  __syncthreads();
#pragma unroll
  for (int c = 0; c < CC; ++c) atomicAdd(&g_sums[c * DD + t], sums[c][t]);
  if (t < CC) atomicAdd(&g_cntf[t], cnts[t]);
}

__global__ void protonorm_k() {
  __shared__ float red[4];
  int t = threadIdx.x;
  int lane = t & 63, w = t >> 6;
  for (int c = 0; c < CC; ++c) {
    float v = g_sums[c * DD + t] / fmaxf(g_cntf[c], 1.0f);
    float sq = wave_sum(v * v);
    if (lane == 0) red[w] = sq;
    __syncthreads();
    float tot = red[0] + red[1] + red[2] + red[3];
    float nrm = fmaxf(sqrtf(tot), 1e-8f);
    g_an[c * DD + t] = v / nrm;
    __syncthreads();
  }
}

// ---------------- cosine similarity + softmax ----------------
__global__ __launch_bounds__(256) void cos_k(const unsigned short* __restrict__ embed,
                                             const int* __restrict__ idxp,
                                             float* __restrict__ out) {
  int wid = (blockIdx.x * 256 + threadIdx.x) >> 6;
  int lane = threadIdx.x & 63;
  if (wid >= MM) return;
  int row = idxp[wid];
  uint2 rv = ((const uint2*)embed)[(size_t)row * 64 + lane];
  float2 r0 = bfpair(rv.x), r1 = bfpair(rv.y);
  float4 r = make_float4(r0.x, r0.y, r1.x, r1.y);
  float n = wave_sum(r.x * r.x + r.y * r.y + r.z * r.z + r.w * r.w);
  float rnf = 1.0f / fmaxf(sqrtf(n), 1e-8f);
  float lg[CC];
#pragma unroll
  for (int c = 0; c < CC; ++c) {
    float4 a = ((const float4*)g_an)[c * 64 + lane];
    float p = r.x * a.x + r.y * a.y + r.z * a.z + r.w * a.w;
    lg[c] = wave_sum(p) * rnf;
  }
  float mx = lg[0];
#pragma unroll
  for (int c = 1; c < CC; ++c) mx = fmaxf(mx, lg[c]);
  float s = 0.f, w[CC];
#pragma unroll
  for (int c = 0; c < CC; ++c) { w[c] = expf(lg[c] - mx); s += w[c]; }
  float inv = 1.f / s;
#pragma unroll
  for (int c = 0; c < CC; ++c)
    if (lane == c) out[(size_t)wid * CC + c] = w[c] * inv;
}

// ---------------- host orchestration ----------------
extern "C" void kernel_launch(void* const* d_in, const int* in_sizes, int n_in,
                              void* d_out, int out_size, void* d_ws, size_t ws_size,
                              hipStream_t stream) {
  (void)in_sizes; (void)n_in; (void)d_ws; (void)ws_size; (void)out_size;
  const float* x      = (const float*)d_in[0];
  const int*   src    = (const int*)d_in[1];
  const int*   dst    = (const int*)d_in[2];
  const int*   idx    = (const int*)d_in[3];
  const int*   labels = (const int*)d_in[4];
  const float* W1 = (const float*)d_in[6];
  const float* b1 = (const float*)d_in[7];
  const float* W2 = (const float*)d_in[8];
  const float* b2 = (const float*)d_in[9];
  const float* W3 = (const float*)d_in[10];
  const float* b3 = (const float*)d_in[11];
  const float* cw_in  = (const float*)d_in[12];
  const float* cb_in  = (const float*)d_in[13];
  const float* cw_hid = (const float*)d_in[14];
  const float* cb_hid = (const float*)d_in[15];
  const float* cw_out = (const float*)d_in[16];
  const float* cb_out = (const float*)d_in[17];
  const float* plist  = (const float*)d_in[18];
  const float* aW     = (const float*)d_in[19];
  const float* ab     = (const float*)d_in[20];
  const float* w2s    = (const float*)d_in[21];
  float* out = (float*)d_out;

  unsigned short *xb, *xo, *hb, *e1b, *e2b, *wt1, *wt2;
  hipGetSymbolAddress((void**)&xb,  HIP_SYMBOL(g_xb));
  hipGetSymbolAddress((void**)&xo,  HIP_SYMBOL(g_xo));
  hipGetSymbolAddress((void**)&hb,  HIP_SYMBOL(g_hb));
  hipGetSymbolAddress((void**)&e1b, HIP_SYMBOL(g_e1b));
  hipGetSymbolAddress((void**)&e2b, HIP_SYMBOL(g_e2b));
  hipGetSymbolAddress((void**)&wt1, HIP_SYMBOL(g_wT1));
  hipGetSymbolAddress((void**)&wt2, HIP_SYMBOL(g_wT2));

  auto WT1 = [&](int w) { return (const unsigned short*)(wt1 + (size_t)w * DD * DD); };
  auto WT2 = [&](int w) { return (const unsigned short*)(wt2 + (size_t)w * DD * DD); };

  // preprocessing
  zero_pre<<<79, 256, 0, stream>>>();
  hist_k<<<1250, 256, 0, stream>>>(dst);
  scanA_k<<<79, 256, 0, stream>>>();
  scanB_k<<<1, 128, 0, stream>>>();
  scanC_k<<<79, 256, 0, stream>>>();
  fill_k<<<1250, 256, 0, stream>>>(src, dst);
  cvt_k<<<2500, 256, 0, stream>>>(x, xb);

  WPtrs wp;
  wp.p[0] = W1; wp.p[1] = W2; wp.p[2] = W3;
  for (int t = 0; t < 3; ++t) {
    wp.p[3 + t] = cw_in  + (size_t)t * DD * DD;
    wp.p[6 + t] = cw_hid + (size_t)t * DD * DD;
    wp.p[9 + t] = cw_out + (size_t)t * DD * DD;
  }
  wprep_k<<<dim3(4, 4, 12), 256, 0, stream>>>(wp);

  const int GG = 628;  // 157 mblk x 4 nblk
  // think layers (e3 dead: gcn_weight1 = gcn_weight3 = 0)
  const unsigned short* xin = xb;
  for (int t = 0; t < TT; ++t) {
    gemm_k<0><<<GG, 256, 0, stream>>>(xin, WT1(0), WT2(0), hb, nullptr, nullptr, nullptr);
    agg_k<0, 0><<<2500, 256, 0, stream>>>(hb, b1, nullptr, e1b);
    gemm_k<0><<<GG, 256, 0, stream>>>(e1b, WT1(1), WT2(1), hb, nullptr, nullptr, nullptr);
    agg_k<0, 1><<<2500, 256, 0, stream>>>(hb, b2, e1b, e2b);
    gemm_k<1><<<GG, 256, 0, stream>>>(e2b, WT1(3 + t), WT2(3 + t), e1b,
                                      cb_in + (size_t)t * DD, w2s, nullptr);
    gemm_k<1><<<GG, 256, 0, stream>>>(e1b, WT1(6 + t), WT2(6 + t), hb,
                                      cb_hid + (size_t)t * DD, nullptr, nullptr);
    gemm_k<2><<<GG, 256, 0, stream>>>(hb, WT1(9 + t), WT2(9 + t), xo,
                                      cb_out + (size_t)t * DD, nullptr, xb);
    xin = xo;
  }

  // final GCN with ELU; last layer fuses prompt attention
  gemm_k<0><<<GG, 256, 0, stream>>>(xin, WT1(0), WT2(0), hb, nullptr, nullptr, nullptr);
  agg_k<1, 0><<<2500, 256, 0, stream>>>(hb, b1, nullptr, e1b);
  gemm_k<0><<<GG, 256, 0, stream>>>(e1b, WT1(1), WT2(1), hb, nullptr, nullptr, nullptr);
  agg_k<1, 0><<<2500, 256, 0, stream>>>(hb, b2, nullptr, e2b);
  gemm_k<0><<<GG, 256, 0, stream>>>(e2b, WT1(2), WT2(2), hb, nullptr, nullptr, nullptr);
  aggattn_k<<<2500, 256, 0, stream>>>(hb, b3, aW, ab, plist, e2b);

  // prototypes + cosine softmax
  proto_k<<<64, 256, 0, stream>>>(e2b, idx, labels);
  protonorm_k<<<1, 256, 0, stream>>>();
  cos_k<<<512, 256, 0, stream>>>(e2b, idx, out);
}

// Round 6
// 631.606 us; speedup vs baseline: 2.3568x; 1.1527x over previous
//
#include <hip/hip_runtime.h>
#include <hip/hip_bf16.h>
#include <math.h>

#define NN 20000
#define DD 256
#define EE 320000
#define MM 2048
#define CC 10
#define TT 3

typedef __attribute__((ext_vector_type(8))) short s8v;
typedef __attribute__((ext_vector_type(4))) float f4v;

// ---------------- device global scratch ----------------
__device__ unsigned short g_xb[NN * DD];   // bf16 original x
__device__ unsigned short g_xo[NN * DD];   // bf16 evolving x
__device__ unsigned short g_hb[NN * DD];
__device__ unsigned short g_e1b[NN * DD];
__device__ unsigned short g_e2b[NN * DD];
__device__ int   g_cnt[NN];
__device__ int   g_cursor[NN];
__device__ int   g_rowstart[NN + 1];
__device__ float g_dinv[NN];
__device__ float g_invdeg[NN];
__device__ int   g_part[128];
__device__ int2  g_edge[EE];     // {src byte-offset, coef bits} in dst-CSR order
__device__ float g_sums[CC * DD];
__device__ float g_cntf[CC];
__device__ float g_an[CC * DD];
// transposed + split weights: wT[n][k], 12 matrices of 256x256 bf16 (hi, lo)
__device__ unsigned short g_wT1[12 * DD * DD];
__device__ unsigned short g_wT2[12 * DD * DD];

__device__ __forceinline__ float wave_sum(float v) {
#pragma unroll
  for (int off = 32; off > 0; off >>= 1) v += __shfl_xor(v, off);
  return v;
}

__device__ __forceinline__ float eluf(float x) {
  return x > 0.f ? x : expm1f(x);
}

__device__ __forceinline__ float bf2f(unsigned short u) {
  union { unsigned int i; float f; } c;
  c.i = (unsigned int)u << 16;
  return c.f;
}

__device__ __forceinline__ float2 bfpair(unsigned int d) {
  union { unsigned int i; float f; } a, b;
  a.i = d << 16;
  b.i = d & 0xffff0000u;
  return make_float2(a.f, b.f);
}

__device__ __forceinline__ unsigned int packbf(float x, float y) {
  union { __hip_bfloat162 v; unsigned int u; } c;
  c.v = __float22bfloat162_rn(make_float2(x, y));
  return c.u;
}

// async 16B global -> LDS (no VGPR cost for in-flight data)
__device__ __forceinline__ void gl_lds16(const unsigned short* g, unsigned short* l) {
  __builtin_amdgcn_global_load_lds(
      (const __attribute__((address_space(1))) unsigned int*)g,
      (__attribute__((address_space(3))) unsigned int*)l, 16, 0, 0);
}

// ---------------- graph preprocessing ----------------
__global__ void zero_pre() {
  int i = blockIdx.x * blockDim.x + threadIdx.x;
  if (i < NN) { g_cnt[i] = 0; g_cursor[i] = 0; }
  if (i < CC * DD) g_sums[i] = 0.f;
  if (i < CC) g_cntf[i] = 0.f;
}

__global__ void hist_k(const int* __restrict__ dst) {
  int e = blockIdx.x * blockDim.x + threadIdx.x;
  if (e < EE) atomicAdd(&g_cnt[dst[e]], 1);
}

// hierarchical scan
__global__ __launch_bounds__(256) void scanA_k() {
  __shared__ int s[256];
  int t = threadIdx.x;
  int i = blockIdx.x * 256 + t;
  int v = (i < NN) ? g_cnt[i] : 0;
  s[t] = v;
  __syncthreads();
#pragma unroll
  for (int off = 128; off > 0; off >>= 1) {
    if (t < off) s[t] += s[t + off];
    __syncthreads();
  }
  if (t == 0) g_part[blockIdx.x] = s[0];
}

__global__ __launch_bounds__(128) void scanB_k() {
  __shared__ int s[128];
  int t = threadIdx.x;
  int p = (t < 79) ? g_part[t] : 0;
  s[t] = p;
  __syncthreads();
#pragma unroll
  for (int off = 1; off < 128; off <<= 1) {
    int v = (t >= off) ? s[t - off] : 0;
    __syncthreads();
    s[t] += v;
    __syncthreads();
  }
  g_part[t] = s[t] - p;  // exclusive
  if (t == 0) g_rowstart[NN] = EE;
}

__global__ __launch_bounds__(256) void scanC_k() {
  __shared__ int s[256];
  int t = threadIdx.x;
  int i = blockIdx.x * 256 + t;
  int v = (i < NN) ? g_cnt[i] : 0;
  s[t] = v;
  __syncthreads();
#pragma unroll
  for (int off = 1; off < 256; off <<= 1) {
    int x = (t >= off) ? s[t - off] : 0;
    __syncthreads();
    s[t] += x;
    __syncthreads();
  }
  if (i < NN) {
    g_rowstart[i] = g_part[blockIdx.x] + s[t] - v;
    float dg = (float)(v + 1);
    g_invdeg[i] = 1.0f / dg;
    g_dinv[i] = 1.0f / sqrtf(dg);
  }
}

__global__ void fill_k(const int* __restrict__ src, const int* __restrict__ dst) {
  int e = blockIdx.x * blockDim.x + threadIdx.x;
  if (e < EE) {
    int d = dst[e];
    int p = atomicAdd(&g_cursor[d], 1);
    int j = g_rowstart[d] + p;
    int si = src[e];
    float coef = g_dinv[si] * g_dinv[d];
    g_edge[j] = make_int2(si * 512, __float_as_int(coef));  // byte offset of row
  }
}

// x fp32 -> bf16
__global__ __launch_bounds__(256) void cvt_k(const float* __restrict__ x,
                                             unsigned short* __restrict__ xb) {
  int i = blockIdx.x * blockDim.x + threadIdx.x;
  const float4* x4 = (const float4*)x;
  float4 a = x4[i * 2], b = x4[i * 2 + 1];
  uint4 o;
  o.x = packbf(a.x, a.y);
  o.y = packbf(a.z, a.w);
  o.z = packbf(b.x, b.y);
  o.w = packbf(b.z, b.w);
  ((uint4*)xb)[i] = o;
}

// ---------------- weight transpose + bf16 split ----------------
struct WPtrs { const float* p[12]; };

__global__ __launch_bounds__(256) void wprep_k(WPtrs wp) {
  __shared__ float t[64][65];
  int widx = blockIdx.z;
  int kt0 = blockIdx.x * 64, nt0 = blockIdx.y * 64;
  const float* W = wp.p[widx];
  int tid = threadIdx.x;
  int ln = tid & 63, lk = tid >> 6;
  for (int kk = lk; kk < 64; kk += 4)
    t[kk][ln] = W[(size_t)(kt0 + kk) * DD + nt0 + ln];
  __syncthreads();
  for (int nn = lk; nn < 64; nn += 4) {
    float v = t[ln][nn];
    __hip_bfloat16 hb = __float2bfloat16(v);
    float hf = __bfloat162float(hb);
    __hip_bfloat16 lb = __float2bfloat16(v - hf);
    union { __hip_bfloat16 b; unsigned short s; } ch, cl;
    ch.b = hb; cl.b = lb;
    size_t o = (size_t)widx * DD * DD + (size_t)(nt0 + nn) * DD + kt0 + ln;
    g_wT1[o] = ch.s;
    g_wT2[o] = cl.s;
  }
}

// ---------------- MFMA GEMM, double-buffered global_load_lds pipeline ----------
// Tile 128x64, BK=64, 4 waves (2x2), frag grid 4mi x 2nj, split-B bf16x2.
// Per buffer (16B chunks): [0,1024)=A(row,pos), [1024,1536)=B1, [1536,2048)=B2,
// pos = kc ^ (row&7) (XOR swizzle on GLOBAL source addr; LDS written linear).
// Two buffers (32KB each); STAGE(t+1) issued before COMPUTE(t); one barrier/iter.
union GemmSM {
  unsigned short st[2 * 2048 * 8];  // 64 KB staging (2 buffers)
  float ct[128][68];                // 34816 B epilogue transpose buffer
};

template <int EPI>
__global__ __launch_bounds__(256) void gemm_k(const unsigned short* __restrict__ A,
                                              const unsigned short* __restrict__ B1,
                                              const unsigned short* __restrict__ B2,
                                              unsigned short* __restrict__ C,
                                              const float* __restrict__ bias,
                                              const float* __restrict__ alphap,
                                              const unsigned short* __restrict__ mul) {
  __shared__ GemmSM sm;
  // bijective chunked XCD swizzle over 628 blocks (79,79,79,79,78,78,78,78)
  int b = blockIdx.x;
  int xcd = b & 7, off = b >> 3;
  int logical = (xcd < 4) ? xcd * 79 + off : 316 + (xcd - 4) * 78 + off;
  int mblk = logical >> 2, nblk = logical & 3;
  int row0 = mblk * 128, col0 = nblk * 64;

  int tid = threadIdx.x;
  int wv = tid >> 6, lane = tid & 63;
  int wm = wv >> 1, wn = wv & 1;
  int lr = lane & 15, lk = lane >> 4;

  f4v acc[4][2];
#pragma unroll
  for (int i = 0; i < 4; ++i)
#pragma unroll
    for (int j = 0; j < 2; ++j) acc[i][j] = (f4v){0.f, 0.f, 0.f, 0.f};

  auto stage = [&](int buf, int kt) {
    unsigned short* base = sm.st + buf * 16384;
#pragma unroll
    for (int i = 0; i < 8; ++i) {
      int cb = (wv * 8 + i) * 64;        // wave-uniform chunk base
      int c = cb + lane;
      unsigned short* ldst = base + (size_t)cb * 8;
      if (cb < 1024) {                   // A region
        int row = c >> 3, kc = c & 7;
        int gr = row0 + row;
        gr = gr < NN ? gr : NN - 1;
        gl_lds16(A + (size_t)gr * DD + kt + ((kc ^ (row & 7)) << 3), ldst);
      } else if (cb < 1536) {            // B1 region
        int c2 = c - 1024;
        int col = c2 >> 3, kc = c2 & 7;
        gl_lds16(B1 + (size_t)(col0 + col) * DD + kt + ((kc ^ (col & 7)) << 3), ldst);
      } else {                           // B2 region
        int c2 = c - 1536;
        int col = c2 >> 3, kc = c2 & 7;
        gl_lds16(B2 + (size_t)(col0 + col) * DD + kt + ((kc ^ (col & 7)) << 3), ldst);
      }
    }
  };

  stage(0, 0);
  __syncthreads();  // drains vmcnt(0): buffer 0 ready

  int buf = 0;
#pragma unroll
  for (int t = 0; t < 4; ++t) {
    if (t < 3) stage(buf ^ 1, (t + 1) * 64);  // issue next tile's loads early
    const unsigned short* base = sm.st + buf * 16384;
#pragma unroll
    for (int ksub = 0; ksub < 2; ++ksub) {
      int kc = ksub * 4 + lk;
      s8v a[4], b1v[2], b2v[2];
#pragma unroll
      for (int mi = 0; mi < 4; ++mi) {
        int row = wm * 64 + mi * 16 + lr;
        a[mi] = *(const s8v*)(base + (row * 8 + (kc ^ (row & 7))) * 8);
      }
#pragma unroll
      for (int nj = 0; nj < 2; ++nj) {
        int col = wn * 32 + nj * 16 + lr;
        int ch = col * 8 + (kc ^ (col & 7));
        b1v[nj] = *(const s8v*)(base + 8192 + ch * 8);
        b2v[nj] = *(const s8v*)(base + 12288 + ch * 8);
      }
#pragma unroll
      for (int mi = 0; mi < 4; ++mi)
#pragma unroll
        for (int nj = 0; nj < 2; ++nj) {
          acc[mi][nj] = __builtin_amdgcn_mfma_f32_16x16x32_bf16(a[mi], b1v[nj], acc[mi][nj], 0, 0, 0);
          acc[mi][nj] = __builtin_amdgcn_mfma_f32_16x16x32_bf16(a[mi], b2v[nj], acc[mi][nj], 0, 0, 0);
        }
    }
    __syncthreads();  // next buffer staged + this buffer's reads done
    buf ^= 1;
  }

  // ---- epilogue: frags -> LDS fp32 -> full-line bf16 stores ----
#pragma unroll
  for (int mi = 0; mi < 4; ++mi)
#pragma unroll
    for (int nj = 0; nj < 2; ++nj)
#pragma unroll
      for (int r = 0; r < 4; ++r)
        sm.ct[wm * 64 + mi * 16 + lk * 4 + r][wn * 32 + nj * 16 + lr] = acc[mi][nj][r];
  __syncthreads();

  float alpha = 1.f;
  if (EPI == 1) alpha = alphap ? *alphap : 1.f;
#pragma unroll
  for (int p = 0; p < 4; ++p) {
    int row = p * 32 + (tid >> 3);
    int c0 = (tid & 7) * 8;
    int gr = row0 + row;
    int gc = col0 + c0;
    if (gr < NN) {
      float v[8];
      float4 va = *(float4*)&sm.ct[row][c0];
      float4 vb = *(float4*)&sm.ct[row][c0 + 4];
      v[0] = va.x; v[1] = va.y; v[2] = va.z; v[3] = va.w;
      v[4] = vb.x; v[5] = vb.y; v[6] = vb.z; v[7] = vb.w;
      if (EPI == 1) {
        float4 bv0 = *(const float4*)(bias + gc);
        float4 bv1 = *(const float4*)(bias + gc + 4);
        float bb[8] = {bv0.x, bv0.y, bv0.z, bv0.w, bv1.x, bv1.y, bv1.z, bv1.w};
#pragma unroll
        for (int i = 0; i < 8; ++i) v[i] = eluf(fmaf(alpha, v[i], bb[i]));
      } else if (EPI == 2) {
        float4 bv0 = *(const float4*)(bias + gc);
        float4 bv1 = *(const float4*)(bias + gc + 4);
        float bb[8] = {bv0.x, bv0.y, bv0.z, bv0.w, bv1.x, bv1.y, bv1.z, bv1.w};
        uint4 mu = *(const uint4*)(mul + (size_t)gr * DD + gc);
        float2 m0 = bfpair(mu.x), m1 = bfpair(mu.y), m2 = bfpair(mu.z), m3 = bfpair(mu.w);
        float mm[8] = {m0.x, m0.y, m1.x, m1.y, m2.x, m2.y, m3.x, m3.y};
#pragma unroll
        for (int i = 0; i < 8; ++i) v[i] = (v[i] + bb[i]) * mm[i];
      }
      uint4 o;
      o.x = packbf(v[0], v[1]);
      o.y = packbf(v[2], v[3]);
      o.z = packbf(v[4], v[5]);
      o.w = packbf(v[6], v[7]);
      *(uint4*)(C + (size_t)gr * DD + gc) = o;
    }
  }
}

// ---------------- CSR aggregation (bf16 rows, fp32 accum, voffset addressing) --
template <int RES>
__device__ __forceinline__ float4 agg_row_b(int row, int lane,
                                            const unsigned short* __restrict__ h,
                                            const float* __restrict__ bias,
                                            const unsigned short* __restrict__ res) {
  const char* hb = (const char*)h;
  int lo = lane * 8;  // lane byte offset within a row
  float4 a = make_float4(0.f, 0.f, 0.f, 0.f);
  int s = g_rowstart[row], e = g_rowstart[row + 1];
  int j = s;
  for (; j + 16 <= e; j += 16) {
    int2 E[16];
    uint2 v[16];
#pragma unroll
    for (int u = 0; u < 16; ++u) E[u] = g_edge[j + u];
#pragma unroll
    for (int u = 0; u < 16; ++u) v[u] = *(const uint2*)(hb + E[u].x + lo);
#pragma unroll
    for (int u = 0; u < 16; ++u) {
      float c = __int_as_float(E[u].y);
      float2 p0 = bfpair(v[u].x), p1 = bfpair(v[u].y);
      a.x = fmaf(c, p0.x, a.x); a.y = fmaf(c, p0.y, a.y);
      a.z = fmaf(c, p1.x, a.z); a.w = fmaf(c, p1.y, a.w);
    }
  }
  for (; j + 4 <= e; j += 4) {
    int2 E[4];
    uint2 v[4];
#pragma unroll
    for (int u = 0; u < 4; ++u) E[u] = g_edge[j + u];
#pragma unroll
    for (int u = 0; u < 4; ++u) v[u] = *(const uint2*)(hb + E[u].x + lo);
#pragma unroll
    for (int u = 0; u < 4; ++u) {
      float c = __int_as_float(E[u].y);
      float2 p0 = bfpair(v[u].x), p1 = bfpair(v[u].y);
      a.x = fmaf(c, p0.x, a.x); a.y = fmaf(c, p0.y, a.y);
      a.z = fmaf(c, p1.x, a.z); a.w = fmaf(c, p1.y, a.w);
    }
  }
  for (; j < e; ++j) {
    int2 E0 = g_edge[j];
    uint2 v0 = *(const uint2*)(hb + E0.x + lo);
    float c = __int_as_float(E0.y);
    float2 p0 = bfpair(v0.x), p1 = bfpair(v0.y);
    a.x = fmaf(c, p0.x, a.x); a.y = fmaf(c, p0.y, a.y);
    a.z = fmaf(c, p1.x, a.z); a.w = fmaf(c, p1.y, a.w);
  }
  float idg = g_invdeg[row];
  uint2 hv = *(const uint2*)(hb + row * 512 + lo);
  float2 h0 = bfpair(hv.x), h1 = bfpair(hv.y);
  float4 bv = ((const float4*)bias)[lane];
  float4 o;
  o.x = a.x + h0.x * idg + bv.x;
  o.y = a.y + h0.y * idg + bv.y;
  o.z = a.z + h1.x * idg + bv.z;
  o.w = a.w + h1.y * idg + bv.w;
  if (RES) {
    uint2 rv = *(const uint2*)((const char*)res + row * 512 + lo);
    float2 r0 = bfpair(rv.x), r1 = bfpair(rv.y);
    o.x += r0.x; o.y += r0.y; o.z += r1.x; o.w += r1.y;
  }
  return o;
}

template <int ELU, int RES>
__global__ __launch_bounds__(256) void agg_k(const unsigned short* __restrict__ h,
                                             const float* __restrict__ bias,
                                             const unsigned short* __restrict__ res,
                                             unsigned short* __restrict__ out) {
  int row = (blockIdx.x * 256 + threadIdx.x) >> 6;  // 1 row per wave, 20000 waves
  int lane = threadIdx.x & 63;
  float4 o = agg_row_b<RES>(row, lane, h, bias, res);
  if (ELU) {
    o.x = eluf(o.x); o.y = eluf(o.y); o.z = eluf(o.z); o.w = eluf(o.w);
  }
  ((uint2*)out)[(size_t)row * 64 + lane] = make_uint2(packbf(o.x, o.y), packbf(o.z, o.w));
}

// final layer: agg + ELU + prompt attention fused
__global__ __launch_bounds__(256) void aggattn_k(const unsigned short* __restrict__ h,
                                                 const float* __restrict__ bias,
                                                 const float* __restrict__ aW,
                                                 const float* __restrict__ ab,
                                                 const float* __restrict__ plist,
                                                 unsigned short* __restrict__ out) {
  int row = (blockIdx.x * 256 + threadIdx.x) >> 6;
  int lane = threadIdx.x & 63;
  float4 o = agg_row_b<0>(row, lane, h, bias, nullptr);
  o.x = eluf(o.x); o.y = eluf(o.y); o.z = eluf(o.z); o.w = eluf(o.w);
  int d = lane * 4;
  float lg[5];
#pragma unroll
  for (int k = 0; k < 5; ++k) {
    float p = o.x * aW[(d + 0) * 5 + k] + o.y * aW[(d + 1) * 5 + k] +
              o.z * aW[(d + 2) * 5 + k] + o.w * aW[(d + 3) * 5 + k];
    lg[k] = wave_sum(p) + ab[k];
  }
  float mx = lg[0];
#pragma unroll
  for (int k = 1; k < 5; ++k) mx = fmaxf(mx, lg[k]);
  float w[5], sum = 0.f;
#pragma unroll
  for (int k = 0; k < 5; ++k) { w[k] = expf(lg[k] - mx); sum += w[k]; }
  float inv = 1.f / sum;
#pragma unroll
  for (int k = 0; k < 5; ++k) {
    float wk = w[k] * inv;
    float4 pv = ((const float4*)plist)[k * 64 + lane];
    o.x = fmaf(wk, pv.x, o.x);
    o.y = fmaf(wk, pv.y, o.y);
    o.z = fmaf(wk, pv.z, o.z);
    o.w = fmaf(wk, pv.w, o.w);
  }
  ((uint2*)out)[(size_t)row * 64 + lane] = make_uint2(packbf(o.x, o.y), packbf(o.z, o.w));
}

// ---------------- class prototypes ----------------
__global__ __launch_bounds__(256) void proto_k(const unsigned short* __restrict__ embed,
                                               const int* __restrict__ idxp,
                                               const int* __restrict__ labels) {
  __shared__ float sums[CC][DD];
  __shared__ float cnts[CC];
  int t = threadIdx.x;
#pragma unroll
  for (int c = 0; c < CC; ++c) sums[c][t] = 0.f;
  if (t < CC) cnts[t] = 0.f;
  __syncthreads();
  int m0 = blockIdx.x * 32;
  for (int r0 = 0; r0 < 32; r0 += 4) {
    int i4[4], l4[4];
    float v[4];
#pragma unroll
    for (int u = 0; u < 4; ++u) {
      int m = m0 + r0 + u;
      i4[u] = idxp[m];
      l4[u] = labels[m];
    }
#pragma unroll
    for (int u = 0; u < 4; ++u) v[u] = bf2f(embed[(size_t)i4[u] * DD + t]);
#pragma unroll
    for (int u = 0; u < 4; ++u) sums[l4[u]][t] += v[u];
    if (t == 0) {
#pragma unroll
      for (int u = 0; u < 4; ++u) cnts[l4[u]] += 1.f;
    }
  }
  __syncthreads();
#pragma unroll
  for (int c = 0; c < CC; ++c) atomicAdd(&g_sums[c * DD + t], sums[c][t]);
  if (t < CC) atomicAdd(&g_cntf[t], cnts[t]);
}

__global__ void protonorm_k() {
  __shared__ float red[4];
  int t = threadIdx.x;
  int lane = t & 63, w = t >> 6;
  for (int c = 0; c < CC; ++c) {
    float v = g_sums[c * DD + t] / fmaxf(g_cntf[c], 1.0f);
    float sq = wave_sum(v * v);
    if (lane == 0) red[w] = sq;
    __syncthreads();
    float tot = red[0] + red[1] + red[2] + red[3];
    float nrm = fmaxf(sqrtf(tot), 1e-8f);
    g_an[c * DD + t] = v / nrm;
    __syncthreads();
  }
}

// ---------------- cosine similarity + softmax ----------------
__global__ __launch_bounds__(256) void cos_k(const unsigned short* __restrict__ embed,
                                             const int* __restrict__ idxp,
                                             float* __restrict__ out) {
  int wid = (blockIdx.x * 256 + threadIdx.x) >> 6;
  int lane = threadIdx.x & 63;
  if (wid >= MM) return;
  int row = idxp[wid];
  uint2 rv = ((const uint2*)embed)[(size_t)row * 64 + lane];
  float2 r0 = bfpair(rv.x), r1 = bfpair(rv.y);
  float4 r = make_float4(r0.x, r0.y, r1.x, r1.y);
  float n = wave_sum(r.x * r.x + r.y * r.y + r.z * r.z + r.w * r.w);
  float rnf = 1.0f / fmaxf(sqrtf(n), 1e-8f);
  float lg[CC];
#pragma unroll
  for (int c = 0; c < CC; ++c) {
    float4 a = ((const float4*)g_an)[c * 64 + lane];
    float p = r.x * a.x + r.y * a.y + r.z * a.z + r.w * a.w;
    lg[c] = wave_sum(p) * rnf;
  }
  float mx = lg[0];
#pragma unroll
  for (int c = 1; c < CC; ++c) mx = fmaxf(mx, lg[c]);
  float s = 0.f, w[CC];
#pragma unroll
  for (int c = 0; c < CC; ++c) { w[c] = expf(lg[c] - mx); s += w[c]; }
  float inv = 1.f / s;
#pragma unroll
  for (int c = 0; c < CC; ++c)
    if (lane == c) out[(size_t)wid * CC + c] = w[c] * inv;
}

// ---------------- host orchestration ----------------
extern "C" void kernel_launch(void* const* d_in, const int* in_sizes, int n_in,
                              void* d_out, int out_size, void* d_ws, size_t ws_size,
                              hipStream_t stream) {
  (void)in_sizes; (void)n_in; (void)d_ws; (void)ws_size; (void)out_size;
  const float* x      = (const float*)d_in[0];
  const int*   src    = (const int*)d_in[1];
  const int*   dst    = (const int*)d_in[2];
  const int*   idx    = (const int*)d_in[3];
  const int*   labels = (const int*)d_in[4];
  const float* W1 = (const float*)d_in[6];
  const float* b1 = (const float*)d_in[7];
  const float* W2 = (const float*)d_in[8];
  const float* b2 = (const float*)d_in[9];
  const float* W3 = (const float*)d_in[10];
  const float* b3 = (const float*)d_in[11];
  const float* cw_in  = (const float*)d_in[12];
  const float* cb_in  = (const float*)d_in[13];
  const float* cw_hid = (const float*)d_in[14];
  const float* cb_hid = (const float*)d_in[15];
  const float* cw_out = (const float*)d_in[16];
  const float* cb_out = (const float*)d_in[17];
  const float* plist  = (const float*)d_in[18];
  const float* aW     = (const float*)d_in[19];
  const float* ab     = (const float*)d_in[20];
  const float* w2s    = (const float*)d_in[21];
  float* out = (float*)d_out;

  unsigned short *xb, *xo, *hb, *e1b, *e2b, *wt1, *wt2;
  hipGetSymbolAddress((void**)&xb,  HIP_SYMBOL(g_xb));
  hipGetSymbolAddress((void**)&xo,  HIP_SYMBOL(g_xo));
  hipGetSymbolAddress((void**)&hb,  HIP_SYMBOL(g_hb));
  hipGetSymbolAddress((void**)&e1b, HIP_SYMBOL(g_e1b));
  hipGetSymbolAddress((void**)&e2b, HIP_SYMBOL(g_e2b));
  hipGetSymbolAddress((void**)&wt1, HIP_SYMBOL(g_wT1));
  hipGetSymbolAddress((void**)&wt2, HIP_SYMBOL(g_wT2));

  auto WT1 = [&](int w) { return (const unsigned short*)(wt1 + (size_t)w * DD * DD); };
  auto WT2 = [&](int w) { return (const unsigned short*)(wt2 + (size_t)w * DD * DD); };

  // preprocessing
  zero_pre<<<79, 256, 0, stream>>>();
  hist_k<<<1250, 256, 0, stream>>>(dst);
  scanA_k<<<79, 256, 0, stream>>>();
  scanB_k<<<1, 128, 0, stream>>>();
  scanC_k<<<79, 256, 0, stream>>>();
  fill_k<<<1250, 256, 0, stream>>>(src, dst);
  cvt_k<<<2500, 256, 0, stream>>>(x, xb);

  WPtrs wp;
  wp.p[0] = W1; wp.p[1] = W2; wp.p[2] = W3;
  for (int t = 0; t < 3; ++t) {
    wp.p[3 + t] = cw_in  + (size_t)t * DD * DD;
    wp.p[6 + t] = cw_hid + (size_t)t * DD * DD;
    wp.p[9 + t] = cw_out + (size_t)t * DD * DD;
  }
  wprep_k<<<dim3(4, 4, 12), 256, 0, stream>>>(wp);

  const int GG = 628;  // 157 mblk x 4 nblk
  // think layers (e3 dead: gcn_weight1 = gcn_weight3 = 0)
  const unsigned short* xin = xb;
  for (int t = 0; t < TT; ++t) {
    gemm_k<0><<<GG, 256, 0, stream>>>(xin, WT1(0), WT2(0), hb, nullptr, nullptr, nullptr);
    agg_k<0, 0><<<5000, 256, 0, stream>>>(hb, b1, nullptr, e1b);
    gemm_k<0><<<GG, 256, 0, stream>>>(e1b, WT1(1), WT2(1), hb, nullptr, nullptr, nullptr);
    agg_k<0, 1><<<5000, 256, 0, stream>>>(hb, b2, e1b, e2b);
    gemm_k<1><<<GG, 256, 0, stream>>>(e2b, WT1(3 + t), WT2(3 + t), e1b,
                                      cb_in + (size_t)t * DD, w2s, nullptr);
    gemm_k<1><<<GG, 256, 0, stream>>>(e1b, WT1(6 + t), WT2(6 + t), hb,
                                      cb_hid + (size_t)t * DD, nullptr, nullptr);
    gemm_k<2><<<GG, 256, 0, stream>>>(hb, WT1(9 + t), WT2(9 + t), xo,
                                      cb_out + (size_t)t * DD, nullptr, xb);
    xin = xo;
  }

  // final GCN with ELU; last layer fuses prompt attention
  gemm_k<0><<<GG, 256, 0, stream>>>(xin, WT1(0), WT2(0), hb, nullptr, nullptr, nullptr);
  agg_k<1, 0><<<5000, 256, 0, stream>>>(hb, b1, nullptr, e1b);
  gemm_k<0><<<GG, 256, 0, stream>>>(e1b, WT1(1), WT2(1), hb, nullptr, nullptr, nullptr);
  agg_k<1, 0><<<5000, 256, 0, stream>>>(hb, b2, nullptr, e2b);
  gemm_k<0><<<GG, 256, 0, stream>>>(e2b, WT1(2), WT2(2), hb, nullptr, nullptr, nullptr);
  aggattn_k<<<5000, 256, 0, stream>>>(hb, b3, aW, ab, plist, e2b);

  // prototypes + cosine softmax
  proto_k<<<64, 256, 0, stream>>>(e2b, idx, labels);
  protonorm_k<<<1, 256, 0, stream>>>();
  cos_k<<<512, 256, 0, stream>>>(e2b, idx, out);
}